// Round 1
// baseline (277.648 us; speedup 1.0000x reference)
//
#include <hip/hip_runtime.h>

typedef short bf16x8 __attribute__((ext_vector_type(8)));
typedef short bf16x4 __attribute__((ext_vector_type(4)));
typedef float f32x4 __attribute__((ext_vector_type(4)));

#define DEVI static __device__ __forceinline__

// f32 -> bf16 round-to-nearest-even
DEVI unsigned short f2b(float f) {
  unsigned u = __float_as_uint(f);
  u += 0x7FFFu + ((u >> 16) & 1u);
  return (unsigned short)(u >> 16);
}

DEVI void gload16(const void* g, void* l) {
  __builtin_amdgcn_global_load_lds((const __attribute__((address_space(1))) void*)g,
                                   (__attribute__((address_space(3))) void*)l, 16, 0, 0);
}

// ------------------------------------------------------------------
// RoPE tables: ct/st[s][j], s<2048, j<32 (f32)
// ------------------------------------------------------------------
__global__ void rope_table_kernel(float* __restrict__ ct, float* __restrict__ st) {
  int i = blockIdx.x * 256 + threadIdx.x;     // 65536 total
  int s = i >> 5, j = i & 31;
  float inv = powf(10000.0f, -(float)j * (1.0f / 32.0f));
  float a = (float)s * inv;
  ct[i] = cosf(a);
  st[i] = sinf(a);
}

// ------------------------------------------------------------------
// x f32 -> bf16 (vectorized)
// ------------------------------------------------------------------
__global__ void cvt_x_kernel(const float* __restrict__ x, unsigned short* __restrict__ xb) {
  int i = blockIdx.x * 256 + threadIdx.x;     // n/4 threads
  float4 v = ((const float4*)x)[i];
  ushort4 o;
  o.x = f2b(v.x); o.y = f2b(v.y); o.z = f2b(v.z); o.w = f2b(v.w);
  ((ushort4*)xb)[i] = o;
}

// ------------------------------------------------------------------
// W [K][N] f32  ->  WT [N][K] bf16  (LDS 32x32 tile transpose)
// ------------------------------------------------------------------
__global__ void transpose_kernel(const float* __restrict__ W, unsigned short* __restrict__ WT,
                                 int K, int N) {
  __shared__ float tile[32][33];
  int n0 = blockIdx.x * 32, k0 = blockIdx.y * 32;
  int tx = threadIdx.x, ty = threadIdx.y;     // 32 x 8
#pragma unroll
  for (int i = 0; i < 32; i += 8)
    tile[ty + i][tx] = W[(size_t)(k0 + ty + i) * N + n0 + tx];
  __syncthreads();
#pragma unroll
  for (int i = 0; i < 32; i += 8)
    WT[(size_t)(n0 + ty + i) * K + k0 + tx] = f2b(tile[tx][ty + i]);
}

// ------------------------------------------------------------------
// Shared GEMM main loop: C[128x128] tile, A [M][1024] bf16, B^T [N][1024] bf16
// 4 waves (2x2), each 64x64 via 4x4 frags of 16x16x32 MFMA, BK=64
// ------------------------------------------------------------------
DEVI void gemm_mainloop(const unsigned short* __restrict__ A, const unsigned short* __restrict__ B,
                        unsigned short* As, unsigned short* Bs,
                        int m0, int n0, int lane, int wid, int wr, int wc,
                        f32x4 acc[4][4]) {
  const int srow = lane >> 3;
  const int scol = (lane & 7) * 8;
  for (int k0 = 0; k0 < 1024; k0 += 64) {
#pragma unroll
    for (int i = 0; i < 4; ++i) {
      const int c = i * 4 + wid;
      const int row = c * 8 + srow;
      gload16(A + (size_t)(m0 + row) * 1024 + k0 + scol, (char*)As + c * 1024);
      gload16(B + (size_t)(n0 + row) * 1024 + k0 + scol, (char*)Bs + c * 1024);
    }
    __syncthreads();
#pragma unroll
    for (int kk = 0; kk < 64; kk += 32) {
      bf16x8 a[4], b[4];
#pragma unroll
      for (int mi = 0; mi < 4; ++mi)
        a[mi] = *(const bf16x8*)&As[(wr * 64 + mi * 16 + (lane & 15)) * 64 + kk + (lane >> 4) * 8];
#pragma unroll
      for (int ni = 0; ni < 4; ++ni)
        b[ni] = *(const bf16x8*)&Bs[(wc * 64 + ni * 16 + (lane & 15)) * 64 + kk + (lane >> 4) * 8];
#pragma unroll
      for (int mi = 0; mi < 4; ++mi)
#pragma unroll
        for (int ni = 0; ni < 4; ++ni)
          acc[mi][ni] = __builtin_amdgcn_mfma_f32_16x16x32_bf16(a[mi], b[ni], acc[mi][ni], 0, 0, 0);
    }
    __syncthreads();
  }
}

// ------------------------------------------------------------------
// GEMM1: qkv = Xb @ WqT^T with fused RoPE; scatter Q[B,H,S,64] K[B,H,S,64] VT[B,H,64,S]
// grid (24, 32)
// ------------------------------------------------------------------
__global__ __launch_bounds__(256) void gemm_qkv_kernel(
    const unsigned short* __restrict__ Xb, const unsigned short* __restrict__ WT,
    const float* __restrict__ ct, const float* __restrict__ st,
    unsigned short* __restrict__ Qb, unsigned short* __restrict__ Kb,
    unsigned short* __restrict__ VTb) {
  __shared__ unsigned short As[128 * 64];
  __shared__ unsigned short Bs[128 * 64];
  const int lane = threadIdx.x & 63, wid = threadIdx.x >> 6;
  const int m0 = blockIdx.y * 128, n0 = blockIdx.x * 128;
  const int wr = wid >> 1, wc = wid & 1;
  f32x4 acc[4][4] = {};
  gemm_mainloop(Xb, WT, As, Bs, m0, n0, lane, wid, wr, wc, acc);

  // wave covers exactly one head: n in [n_base, n_base+64)
  const int n_base = n0 + wc * 64;
  const int t = n_base >> 10;                 // 0=q 1=k 2=v
  const int h = (n_base & 1023) >> 6;
  if (t < 2) {
    unsigned short* dst = (t == 0) ? Qb : Kb;
#pragma unroll
    for (int mi = 0; mi < 4; ++mi) {
      const int mrow = m0 + wr * 64 + mi * 16 + ((lane >> 4) << 2);
#pragma unroll
      for (int r = 0; r < 4; ++r) {
        const int m = mrow + r;
        const int s = m & 2047, bb = m >> 11;
        const size_t base = ((size_t)(bb * 16 + h) * 2048 + s) * 64;
#pragma unroll
        for (int ni = 0; ni < 2; ++ni) {
          const int j = ni * 16 + (lane & 15);
          const float c = ct[s * 32 + j], sn = st[s * 32 + j];
          const float x1 = acc[mi][ni][r], x2 = acc[mi][ni + 2][r];
          dst[base + j]      = f2b(x1 * c + x2 * sn);
          dst[base + j + 32] = f2b(-x1 * sn + x2 * c);
        }
      }
    }
  } else {
#pragma unroll
    for (int mi = 0; mi < 4; ++mi) {
      const int mrow = m0 + wr * 64 + mi * 16 + ((lane >> 4) << 2);
      const int s = mrow & 2047, bb = mrow >> 11;
#pragma unroll
      for (int ni = 0; ni < 4; ++ni) {
        const int d = ni * 16 + (lane & 15);
        ushort4 o;
        o.x = f2b(acc[mi][ni][0]); o.y = f2b(acc[mi][ni][1]);
        o.z = f2b(acc[mi][ni][2]); o.w = f2b(acc[mi][ni][3]);
        *(ushort4*)&VTb[((size_t)(bb * 16 + h) * 64 + d) * 2048 + s] = o;
      }
    }
  }
}

// ------------------------------------------------------------------
// Flash attention (causal). grid (16, 32): x = q-block (reversed), y = b*16+h.
// 4 waves/block, 32 q rows/wave (2 subtiles of 16). No LDS (K/V are L2-resident).
// S^T = mfma(K, Q): D layout col=q=lane&15, row=key=(lane>>4)*4+r — feeds PV A directly.
// ------------------------------------------------------------------
__global__ __launch_bounds__(256) void attn_kernel(
    const unsigned short* __restrict__ Qb, const unsigned short* __restrict__ Kb,
    const unsigned short* __restrict__ VTb, unsigned short* __restrict__ Ob) {
  const int lane = threadIdx.x & 63, wid = threadIdx.x >> 6;
  const int bh = blockIdx.y;
  const int qblk = (int)gridDim.x - 1 - (int)blockIdx.x;  // heavy blocks first
  const int q0 = qblk * 128 + wid * 32;
  const unsigned short* Qh = Qb + (size_t)bh * 2048 * 64;
  const unsigned short* Kh = Kb + (size_t)bh * 2048 * 64;
  const unsigned short* Vh = VTb + (size_t)bh * 64 * 2048;

  bf16x8 qf[2][2];
#pragma unroll
  for (int s2 = 0; s2 < 2; ++s2) {
    const unsigned short* p = Qh + (size_t)(q0 + s2 * 16 + (lane & 15)) * 64 + ((lane >> 4) << 3);
    qf[s2][0] = *(const bf16x8*)p;
    qf[s2][1] = *(const bf16x8*)(p + 32);
  }
  f32x4 acc[2][4] = {};
  float m_run[2] = {-1e30f, -1e30f}, l_run[2] = {0.f, 0.f};
  const int qtop0 = q0 + 15, qtop1 = q0 + 31;
  const int nsteps = q0 / 16 + 2;

  for (int kb = 0; kb < nsteps; ++kb) {
    const int kbase = kb * 16;
    const unsigned short* kp = Kh + (size_t)(kbase + (lane & 15)) * 64 + ((lane >> 4) << 3);
    const bf16x8 kf0 = *(const bf16x8*)kp;
    const bf16x8 kf1 = *(const bf16x8*)(kp + 32);
    bf16x4 vf[4];
#pragma unroll
    for (int db = 0; db < 4; ++db)
      vf[db] = *(const bf16x4*)(Vh + (size_t)(db * 16 + (lane & 15)) * 2048 + kbase + ((lane >> 4) << 2));
#pragma unroll
    for (int s2 = 0; s2 < 2; ++s2) {
      const int qtop = (s2 == 0) ? qtop0 : qtop1;
      if (kbase > qtop) continue;           // wave-uniform
      f32x4 stv = {};
      stv = __builtin_amdgcn_mfma_f32_16x16x32_bf16(kf0, qf[s2][0], stv, 0, 0, 0);
      stv = __builtin_amdgcn_mfma_f32_16x16x32_bf16(kf1, qf[s2][1], stv, 0, 0, 0);
      const int qg = q0 + s2 * 16 + (lane & 15);
      float sv[4], mstep = -1e30f;
#pragma unroll
      for (int r = 0; r < 4; ++r) {
        const int kg = kbase + ((lane >> 4) << 2) + r;
        const float v = stv[r] * 0.125f;
        sv[r] = (kg <= qg) ? v : -1e30f;
        mstep = fmaxf(mstep, sv[r]);
      }
      mstep = fmaxf(mstep, __shfl_xor(mstep, 16));
      mstep = fmaxf(mstep, __shfl_xor(mstep, 32));
      const float mnew = fmaxf(m_run[s2], mstep);
      const float scale = exp2f((m_run[s2] - mnew) * 1.44269504f);
      float p[4], ps = 0.f;
#pragma unroll
      for (int r = 0; r < 4; ++r) { p[r] = exp2f((sv[r] - mnew) * 1.44269504f); ps += p[r]; }
      ps += __shfl_xor(ps, 16);
      ps += __shfl_xor(ps, 32);
      l_run[s2] = l_run[s2] * scale + ps;
      m_run[s2] = mnew;
      // redistribute per-q scale to acc rows q' = (lane>>4)*4 + r (source lanes 0..15 hold q=lane)
      float sclr[4];
#pragma unroll
      for (int r = 0; r < 4; ++r) sclr[r] = __shfl(scale, ((lane >> 4) << 2) + r);
#pragma unroll
      for (int db = 0; db < 4; ++db)
#pragma unroll
        for (int r = 0; r < 4; ++r) acc[s2][db][r] *= sclr[r];
      bf16x4 pf;
#pragma unroll
      for (int r = 0; r < 4; ++r) pf[r] = (short)f2b(p[r]);
#pragma unroll
      for (int db = 0; db < 4; ++db)
        acc[s2][db] = __builtin_amdgcn_mfma_f32_16x16x16bf16_1k(pf, vf[db], acc[s2][db], 0, 0, 0);
    }
  }

  const int b = bh >> 4, h = bh & 15;
#pragma unroll
  for (int s2 = 0; s2 < 2; ++s2) {
    const float il = 1.0f / l_run[s2];
    float ilr[4];
#pragma unroll
    for (int r = 0; r < 4; ++r) ilr[r] = __shfl(il, ((lane >> 4) << 2) + r);
#pragma unroll
    for (int db = 0; db < 4; ++db)
#pragma unroll
      for (int r = 0; r < 4; ++r) {
        const int q = q0 + s2 * 16 + ((lane >> 4) << 2) + r;
        const int d = db * 16 + (lane & 15);
        Ob[((size_t)(b * 2048 + q)) * 1024 + h * 64 + d] = f2b(acc[s2][db][r] * ilr[r]);
      }
  }
}

// ------------------------------------------------------------------
// GEMM2: out = Ob @ WoT^T, f32 epilogue. grid (8, 32)
// ------------------------------------------------------------------
__global__ __launch_bounds__(256) void gemm_out_kernel(
    const unsigned short* __restrict__ Ob, const unsigned short* __restrict__ WoT,
    float* __restrict__ out) {
  __shared__ unsigned short As[128 * 64];
  __shared__ unsigned short Bs[128 * 64];
  const int lane = threadIdx.x & 63, wid = threadIdx.x >> 6;
  const int m0 = blockIdx.y * 128, n0 = blockIdx.x * 128;
  const int wr = wid >> 1, wc = wid & 1;
  f32x4 acc[4][4] = {};
  gemm_mainloop(Ob, WoT, As, Bs, m0, n0, lane, wid, wr, wc, acc);
#pragma unroll
  for (int mi = 0; mi < 4; ++mi) {
    const int mrow = m0 + wr * 64 + mi * 16 + ((lane >> 4) << 2);
#pragma unroll
    for (int ni = 0; ni < 4; ++ni) {
      const int n = n0 + wc * 64 + ni * 16 + (lane & 15);
#pragma unroll
      for (int r = 0; r < 4; ++r)
        out[(size_t)(mrow + r) * 1024 + n] = acc[mi][ni][r];
    }
  }
}

// ------------------------------------------------------------------
extern "C" void kernel_launch(void* const* d_in, const int* in_sizes, int n_in,
                              void* d_out, int out_size, void* d_ws, size_t ws_size,
                              hipStream_t stream) {
  const float* x     = (const float*)d_in[0];
  const float* w_qkv = (const float*)d_in[1];
  const float* w_o   = (const float*)d_in[2];
  float* out = (float*)d_out;
  char* ws = (char*)d_ws;

  const size_t MB = 1 << 20;
  float* ct = (float*)(ws);                          // 256 KB
  float* st = (float*)(ws + (256 << 10));            // 256 KB
  unsigned short* Xb  = (unsigned short*)(ws + (512 << 10));            // 8 MB  (reused as Ob)
  unsigned short* WqT = (unsigned short*)(ws + (512 << 10) + 8  * MB);  // 6 MB
  unsigned short* WoT = (unsigned short*)(ws + (512 << 10) + 14 * MB);  // 2 MB
  unsigned short* Qb  = (unsigned short*)(ws + (512 << 10) + 16 * MB);  // 8 MB
  unsigned short* Kb  = (unsigned short*)(ws + (512 << 10) + 24 * MB);  // 8 MB
  unsigned short* VTb = (unsigned short*)(ws + (512 << 10) + 32 * MB);  // 8 MB
  unsigned short* Ob  = Xb;  // Xb dead after gemm1; total ws = 40.5 MB

  rope_table_kernel<<<dim3(256), dim3(256), 0, stream>>>(ct, st);
  cvt_x_kernel<<<dim3(4096), dim3(256), 0, stream>>>(x, Xb);
  transpose_kernel<<<dim3(96, 32), dim3(32, 8), 0, stream>>>(w_qkv, WqT, 1024, 3072);
  transpose_kernel<<<dim3(32, 32), dim3(32, 8), 0, stream>>>(w_o, WoT, 1024, 1024);
  gemm_qkv_kernel<<<dim3(24, 32), dim3(256), 0, stream>>>(Xb, WqT, ct, st, Qb, Kb, VTb);
  attn_kernel<<<dim3(16, 32), dim3(256), 0, stream>>>(Qb, Kb, VTb, Ob);
  gemm_out_kernel<<<dim3(8, 32), dim3(256), 0, stream>>>(Ob, WoT, out);
}

// Round 2
// 187.006 us; speedup vs baseline: 1.4847x; 1.4847x over previous
//
#include <hip/hip_runtime.h>

typedef short bf16x8 __attribute__((ext_vector_type(8)));
typedef short bf16x4 __attribute__((ext_vector_type(4)));
typedef float f32x4 __attribute__((ext_vector_type(4)));
typedef float f32x16 __attribute__((ext_vector_type(16)));
typedef int i32x4 __attribute__((ext_vector_type(4)));

#define DEVI static __device__ __forceinline__

template <bool B> struct BoolC { static constexpr bool value = B; };

// f32 -> bf16 round-to-nearest-even
DEVI unsigned short f2b(float f) {
  unsigned u = __float_as_uint(f);
  u += 0x7FFFu + ((u >> 16) & 1u);
  return (unsigned short)(u >> 16);
}

DEVI void gload16(const void* g, void* l) {
  __builtin_amdgcn_global_load_lds((const __attribute__((address_space(1))) void*)g,
                                   (__attribute__((address_space(3))) void*)l, 16, 0, 0);
}

// permlane32_swap: outa = {a.row0, b.row0}, outb = {a.row1, b.row1}
DEVI void pl32swap(int a, int b, int& outa, int& outb) {
#if __has_builtin(__builtin_amdgcn_permlane32_swap)
  auto r = __builtin_amdgcn_permlane32_swap(a, b, false, false);
  outa = ((const int*)&r)[0];
  outb = ((const int*)&r)[1];
#else
  int bp = __shfl_xor(b, 32);
  int ap = __shfl_xor(a, 32);
  outa = (threadIdx.x & 32) ? bp : a;
  outb = (threadIdx.x & 32) ? b : ap;
#endif
}

// ------------------------------------------------------------------
// RoPE tables: ct/st[s][j], s<2048, j<32 (f32)
// ------------------------------------------------------------------
__global__ void rope_table_kernel(float* __restrict__ ct, float* __restrict__ st) {
  int i = blockIdx.x * 256 + threadIdx.x;     // 65536 total
  int s = i >> 5, j = i & 31;
  float inv = powf(10000.0f, -(float)j * (1.0f / 32.0f));
  float a = (float)s * inv;
  ct[i] = cosf(a);
  st[i] = sinf(a);
}

// ------------------------------------------------------------------
// x f32 -> bf16 (vectorized)
// ------------------------------------------------------------------
__global__ void cvt_x_kernel(const float* __restrict__ x, unsigned short* __restrict__ xb) {
  int i = blockIdx.x * 256 + threadIdx.x;     // n/4 threads
  float4 v = ((const float4*)x)[i];
  ushort4 o;
  o.x = f2b(v.x); o.y = f2b(v.y); o.z = f2b(v.z); o.w = f2b(v.w);
  ((ushort4*)xb)[i] = o;
}

// ------------------------------------------------------------------
// W [K][N] f32  ->  WT [N][K] bf16  (LDS 32x32 tile transpose)
// ------------------------------------------------------------------
__global__ void transpose_kernel(const float* __restrict__ W, unsigned short* __restrict__ WT,
                                 int K, int N) {
  __shared__ float tile[32][33];
  int n0 = blockIdx.x * 32, k0 = blockIdx.y * 32;
  int tx = threadIdx.x, ty = threadIdx.y;     // 32 x 8
#pragma unroll
  for (int i = 0; i < 32; i += 8)
    tile[ty + i][tx] = W[(size_t)(k0 + ty + i) * N + n0 + tx];
  __syncthreads();
#pragma unroll
  for (int i = 0; i < 32; i += 8)
    WT[(size_t)(n0 + ty + i) * K + k0 + tx] = f2b(tile[tx][ty + i]);
}

// ------------------------------------------------------------------
// Shared GEMM main loop: C[128x128] tile, A [M][1024] bf16, B^T [N][1024] bf16
// 4 waves (2x2), each 64x64 via 4x4 frags of 16x16x32 MFMA, BK=64
// ------------------------------------------------------------------
DEVI void gemm_mainloop(const unsigned short* __restrict__ A, const unsigned short* __restrict__ B,
                        unsigned short* As, unsigned short* Bs,
                        int m0, int n0, int lane, int wid, int wr, int wc,
                        f32x4 acc[4][4]) {
  const int srow = lane >> 3;
  const int scol = (lane & 7) * 8;
  for (int k0 = 0; k0 < 1024; k0 += 64) {
#pragma unroll
    for (int i = 0; i < 4; ++i) {
      const int c = i * 4 + wid;
      const int row = c * 8 + srow;
      gload16(A + (size_t)(m0 + row) * 1024 + k0 + scol, (char*)As + c * 1024);
      gload16(B + (size_t)(n0 + row) * 1024 + k0 + scol, (char*)Bs + c * 1024);
    }
    __syncthreads();
#pragma unroll
    for (int kk = 0; kk < 64; kk += 32) {
      bf16x8 a[4], b[4];
#pragma unroll
      for (int mi = 0; mi < 4; ++mi)
        a[mi] = *(const bf16x8*)&As[(wr * 64 + mi * 16 + (lane & 15)) * 64 + kk + (lane >> 4) * 8];
#pragma unroll
      for (int ni = 0; ni < 4; ++ni)
        b[ni] = *(const bf16x8*)&Bs[(wc * 64 + ni * 16 + (lane & 15)) * 64 + kk + (lane >> 4) * 8];
#pragma unroll
      for (int mi = 0; mi < 4; ++mi)
#pragma unroll
        for (int ni = 0; ni < 4; ++ni)
          acc[mi][ni] = __builtin_amdgcn_mfma_f32_16x16x32_bf16(a[mi], b[ni], acc[mi][ni], 0, 0, 0);
    }
    __syncthreads();
  }
}

// ------------------------------------------------------------------
// GEMM1: qkv = Xb @ WqT^T with fused RoPE; scatter Q[B,H,S,64] K[B,H,S,64] VT[B,H,64,S]
// grid (24, 32)
// ------------------------------------------------------------------
__global__ __launch_bounds__(256) void gemm_qkv_kernel(
    const unsigned short* __restrict__ Xb, const unsigned short* __restrict__ WT,
    const float* __restrict__ ct, const float* __restrict__ st,
    unsigned short* __restrict__ Qb, unsigned short* __restrict__ Kb,
    unsigned short* __restrict__ VTb) {
  __shared__ unsigned short As[128 * 64];
  __shared__ unsigned short Bs[128 * 64];
  const int lane = threadIdx.x & 63, wid = threadIdx.x >> 6;
  const int m0 = blockIdx.y * 128, n0 = blockIdx.x * 128;
  const int wr = wid >> 1, wc = wid & 1;
  f32x4 acc[4][4] = {};
  gemm_mainloop(Xb, WT, As, Bs, m0, n0, lane, wid, wr, wc, acc);

  // wave covers exactly one head: n in [n_base, n_base+64)
  const int n_base = n0 + wc * 64;
  const int t = n_base >> 10;                 // 0=q 1=k 2=v
  const int h = (n_base & 1023) >> 6;
  if (t < 2) {
    unsigned short* dst = (t == 0) ? Qb : Kb;
#pragma unroll
    for (int mi = 0; mi < 4; ++mi) {
      const int mrow = m0 + wr * 64 + mi * 16 + ((lane >> 4) << 2);
#pragma unroll
      for (int r = 0; r < 4; ++r) {
        const int m = mrow + r;
        const int s = m & 2047, bb = m >> 11;
        const size_t base = ((size_t)(bb * 16 + h) * 2048 + s) * 64;
#pragma unroll
        for (int ni = 0; ni < 2; ++ni) {
          const int j = ni * 16 + (lane & 15);
          const float c = ct[s * 32 + j], sn = st[s * 32 + j];
          const float x1 = acc[mi][ni][r], x2 = acc[mi][ni + 2][r];
          dst[base + j]      = f2b(x1 * c + x2 * sn);
          dst[base + j + 32] = f2b(-x1 * sn + x2 * c);
        }
      }
    }
  } else {
#pragma unroll
    for (int mi = 0; mi < 4; ++mi) {
      const int mrow = m0 + wr * 64 + mi * 16 + ((lane >> 4) << 2);
      const int s = mrow & 2047, bb = mrow >> 11;
#pragma unroll
      for (int ni = 0; ni < 4; ++ni) {
        const int d = ni * 16 + (lane & 15);
        ushort4 o;
        o.x = f2b(acc[mi][ni][0]); o.y = f2b(acc[mi][ni][1]);
        o.z = f2b(acc[mi][ni][2]); o.w = f2b(acc[mi][ni][3]);
        *(ushort4*)&VTb[((size_t)(bb * 16 + h) * 64 + d) * 2048 + s] = o;
      }
    }
  }
}

// ------------------------------------------------------------------
// Flash attention v2 (causal). grid (32, 16): x = bh (XCD-clustered: flat&7 = bh&7),
// y = q-block group (reversed). 4 waves/block, 32 q rows/wave via 32x32x16 MFMA.
// S^T = mfma(K,Q): col=q=lane&31 -> softmax state lane-local per q.
// O^T = mfma(V^T, P^T): col=q=lane&31 -> rescale / 1/l lane-local too.
// P^T fragments in-register via cvt_pk_bf16 + permlane32_swap (T12).
// Defer-max rescale (T13, THR=8 nats). No LDS, no barriers.
// ------------------------------------------------------------------
__global__ __launch_bounds__(256) void attn_kernel(
    const unsigned short* __restrict__ Qb, const unsigned short* __restrict__ Kb,
    const unsigned short* __restrict__ VTb, unsigned short* __restrict__ Ob) {
  const int lane = threadIdx.x & 63, wid = threadIdx.x >> 6;
  const int ln = lane & 31, hi = lane >> 5;
  const int bh = blockIdx.x;
  const int jblk = (int)gridDim.y - 1 - (int)blockIdx.y;  // heavy blocks first
  const int q0 = jblk * 128 + wid * 32;
  const unsigned short* Qh = Qb + (size_t)bh * 2048 * 64;
  const unsigned short* Kh = Kb + (size_t)bh * 2048 * 64;
  const unsigned short* Vh = VTb + (size_t)bh * 64 * 2048;

  // Q fragments (B-operand: n=q=ln, k=d=t*16+hi*8+j)
  bf16x8 qf[4];
  {
    const unsigned short* p = Qh + (size_t)(q0 + ln) * 64 + hi * 8;
#pragma unroll
    for (int t = 0; t < 4; ++t) qf[t] = *(const bf16x8*)(p + t * 16);
  }

  f32x16 acc0 = {}, acc1 = {};
  float m2 = -1e30f, l_run = 0.f;           // log2-domain running max / denom
  const float C = 0.125f * 1.44269504f;     // scale * log2(e)
  const int qg = q0 + ln;
  const int ntiles = q0 / 32 + 1;

  auto step = [&](int kbase, auto DIAGC) {
    constexpr bool DIAG = DIAGC.value;
    // K fragments (A-operand: m=key=ln, k=d)
    const unsigned short* kp = Kh + (size_t)(kbase + ln) * 64 + hi * 8;
    const bf16x8 kf0 = *(const bf16x8*)kp;
    const bf16x8 kf1 = *(const bf16x8*)(kp + 16);
    const bf16x8 kf2 = *(const bf16x8*)(kp + 32);
    const bf16x8 kf3 = *(const bf16x8*)(kp + 48);
    // V^T fragments (A-operand for PV: m=d_local=ln, k=key=ks*16+hi*8+j)
    const unsigned short* vp = Vh + (size_t)ln * 2048 + kbase + hi * 8;
    const bf16x8 vf00 = *(const bf16x8*)vp;
    const bf16x8 vf01 = *(const bf16x8*)(vp + 16);
    const bf16x8 vf10 = *(const bf16x8*)(vp + 32 * 2048);
    const bf16x8 vf11 = *(const bf16x8*)(vp + 32 * 2048 + 16);

    f32x16 stv = {};
    __builtin_amdgcn_s_setprio(1);
    stv = __builtin_amdgcn_mfma_f32_32x32x16_bf16(kf0, qf[0], stv, 0, 0, 0);
    stv = __builtin_amdgcn_mfma_f32_32x32x16_bf16(kf1, qf[1], stv, 0, 0, 0);
    stv = __builtin_amdgcn_mfma_f32_32x32x16_bf16(kf2, qf[2], stv, 0, 0, 0);
    stv = __builtin_amdgcn_mfma_f32_32x32x16_bf16(kf3, qf[3], stv, 0, 0, 0);
    __builtin_amdgcn_s_setprio(0);

    // lane holds S^T[key = kbase+(r&3)+8*(r>>2)+4*hi][q = ln], r=0..15
    float p[16];
    float mloc = -1e30f;
#pragma unroll
    for (int r = 0; r < 16; ++r) {
      float v = stv[r] * C;
      if constexpr (DIAG) {
        const int kg = kbase + (r & 3) + ((r >> 2) << 3) + (hi << 2);
        v = (kg <= qg) ? v : -1e30f;
      }
      p[r] = v;
      mloc = fmaxf(mloc, v);
    }
    mloc = fmaxf(mloc, __shfl_xor(mloc, 32));
    // defer-max: only rescale acc when max grew by >8 nats (11.54 in log2)
    if (__any(mloc > m2 + 11.5416f)) {
      const float mnew = fmaxf(m2, mloc);
      const float sc = exp2f(m2 - mnew);
      l_run *= sc;
#pragma unroll
      for (int r = 0; r < 16; ++r) { acc0[r] *= sc; acc1[r] *= sc; }
      m2 = mnew;
    }
    float ps = 0.f;
#pragma unroll
    for (int r = 0; r < 16; ++r) { p[r] = exp2f(p[r] - m2); ps += p[r]; }
    ps += __shfl_xor(ps, 32);
    l_run += ps;

    // P^T -> bf16 fragments (B-operand: n=q=ln, k=key_local=hi*8+j)
    int cw[8];
#pragma unroll
    for (int i = 0; i < 8; ++i)
      asm("v_cvt_pk_bf16_f32 %0, %1, %2" : "=v"(cw[i]) : "v"(p[2 * i]), "v"(p[2 * i + 1]));
    int a0, a1, b0, b1, a2, a3, b2, b3;
    pl32swap(cw[0], cw[2], a0, b0);   // slice 0 (keys kbase+0..15): words 0,2
    pl32swap(cw[1], cw[3], a1, b1);   //                              words 1,3
    pl32swap(cw[4], cw[6], a2, b2);   // slice 1 (keys kbase+16..31)
    pl32swap(cw[5], cw[7], a3, b3);
    const bf16x8 pa0 = __builtin_bit_cast(bf16x8, (i32x4){a0, a1, b0, b1});
    const bf16x8 pa1 = __builtin_bit_cast(bf16x8, (i32x4){a2, a3, b2, b3});

    __builtin_amdgcn_s_setprio(1);
    acc0 = __builtin_amdgcn_mfma_f32_32x32x16_bf16(vf00, pa0, acc0, 0, 0, 0);
    acc0 = __builtin_amdgcn_mfma_f32_32x32x16_bf16(vf01, pa1, acc0, 0, 0, 0);
    acc1 = __builtin_amdgcn_mfma_f32_32x32x16_bf16(vf10, pa0, acc1, 0, 0, 0);
    acc1 = __builtin_amdgcn_mfma_f32_32x32x16_bf16(vf11, pa1, acc1, 0, 0, 0);
    __builtin_amdgcn_s_setprio(0);
  };

  for (int kb = 0; kb < ntiles - 1; ++kb) step(kb * 32, BoolC<false>{});
  step((ntiles - 1) * 32, BoolC<true>{});

  // O^T: lane holds O[q=ln][d = dt*32 + (r&3)+8*(r>>2)+4*hi]
  const float il = 1.0f / l_run;
  const int b = bh >> 4, h = bh & 15;
  unsigned short* ob = Ob + ((size_t)(b * 2048 + qg)) * 1024 + h * 64;
#pragma unroll
  for (int g = 0; g < 4; ++g) {
    ushort4 o0, o1;
    o0.x = f2b(acc0[4 * g + 0] * il); o0.y = f2b(acc0[4 * g + 1] * il);
    o0.z = f2b(acc0[4 * g + 2] * il); o0.w = f2b(acc0[4 * g + 3] * il);
    o1.x = f2b(acc1[4 * g + 0] * il); o1.y = f2b(acc1[4 * g + 1] * il);
    o1.z = f2b(acc1[4 * g + 2] * il); o1.w = f2b(acc1[4 * g + 3] * il);
    *(ushort4*)&ob[8 * g + 4 * hi]      = o0;   // dt=0
    *(ushort4*)&ob[32 + 8 * g + 4 * hi] = o1;   // dt=1
  }
}

// ------------------------------------------------------------------
// GEMM2: out = Ob @ WoT^T, f32 epilogue. grid (8, 32)
// ------------------------------------------------------------------
__global__ __launch_bounds__(256) void gemm_out_kernel(
    const unsigned short* __restrict__ Ob, const unsigned short* __restrict__ WoT,
    float* __restrict__ out) {
  __shared__ unsigned short As[128 * 64];
  __shared__ unsigned short Bs[128 * 64];
  const int lane = threadIdx.x & 63, wid = threadIdx.x >> 6;
  const int m0 = blockIdx.y * 128, n0 = blockIdx.x * 128;
  const int wr = wid >> 1, wc = wid & 1;
  f32x4 acc[4][4] = {};
  gemm_mainloop(Ob, WoT, As, Bs, m0, n0, lane, wid, wr, wc, acc);
#pragma unroll
  for (int mi = 0; mi < 4; ++mi) {
    const int mrow = m0 + wr * 64 + mi * 16 + ((lane >> 4) << 2);
#pragma unroll
    for (int ni = 0; ni < 4; ++ni) {
      const int n = n0 + wc * 64 + ni * 16 + (lane & 15);
#pragma unroll
      for (int r = 0; r < 4; ++r)
        out[(size_t)(mrow + r) * 1024 + n] = acc[mi][ni][r];
    }
  }
}

// ------------------------------------------------------------------
extern "C" void kernel_launch(void* const* d_in, const int* in_sizes, int n_in,
                              void* d_out, int out_size, void* d_ws, size_t ws_size,
                              hipStream_t stream) {
  const float* x     = (const float*)d_in[0];
  const float* w_qkv = (const float*)d_in[1];
  const float* w_o   = (const float*)d_in[2];
  float* out = (float*)d_out;
  char* ws = (char*)d_ws;

  const size_t MB = 1 << 20;
  float* ct = (float*)(ws);                          // 256 KB
  float* st = (float*)(ws + (256 << 10));            // 256 KB
  unsigned short* Xb  = (unsigned short*)(ws + (512 << 10));            // 8 MB  (reused as Ob)
  unsigned short* WqT = (unsigned short*)(ws + (512 << 10) + 8  * MB);  // 6 MB
  unsigned short* WoT = (unsigned short*)(ws + (512 << 10) + 14 * MB);  // 2 MB
  unsigned short* Qb  = (unsigned short*)(ws + (512 << 10) + 16 * MB);  // 8 MB
  unsigned short* Kb  = (unsigned short*)(ws + (512 << 10) + 24 * MB);  // 8 MB
  unsigned short* VTb = (unsigned short*)(ws + (512 << 10) + 32 * MB);  // 8 MB
  unsigned short* Ob  = Xb;  // Xb dead after gemm1; total ws = 40.5 MB

  rope_table_kernel<<<dim3(256), dim3(256), 0, stream>>>(ct, st);
  cvt_x_kernel<<<dim3(4096), dim3(256), 0, stream>>>(x, Xb);
  transpose_kernel<<<dim3(96, 32), dim3(32, 8), 0, stream>>>(w_qkv, WqT, 1024, 3072);
  transpose_kernel<<<dim3(32, 32), dim3(32, 8), 0, stream>>>(w_o, WoT, 1024, 1024);
  gemm_qkv_kernel<<<dim3(24, 32), dim3(256), 0, stream>>>(Xb, WqT, ct, st, Qb, Kb, VTb);
  attn_kernel<<<dim3(32, 16), dim3(256), 0, stream>>>(Qb, Kb, VTb, Ob);
  gemm_out_kernel<<<dim3(8, 32), dim3(256), 0, stream>>>(Ob, WoT, out);
}

// Round 3
// 162.599 us; speedup vs baseline: 1.7076x; 1.1501x over previous
//
#include <hip/hip_runtime.h>

typedef short bf16x8 __attribute__((ext_vector_type(8)));
typedef short bf16x4 __attribute__((ext_vector_type(4)));
typedef float f32x4 __attribute__((ext_vector_type(4)));
typedef float f32x16 __attribute__((ext_vector_type(16)));
typedef int i32x4 __attribute__((ext_vector_type(4)));

#define DEVI static __device__ __forceinline__

// f32 -> bf16 round-to-nearest-even
DEVI unsigned short f2b(float f) {
  unsigned u = __float_as_uint(f);
  u += 0x7FFFu + ((u >> 16) & 1u);
  return (unsigned short)(u >> 16);
}

DEVI void gload16(const void* g, void* l) {
  __builtin_amdgcn_global_load_lds((const __attribute__((address_space(1))) void*)g,
                                   (__attribute__((address_space(3))) void*)l, 16, 0, 0);
}

// permlane32_swap: outa = {a.row0, b.row0}, outb = {a.row1, b.row1}
DEVI void pl32swap(int a, int b, int& outa, int& outb) {
#if __has_builtin(__builtin_amdgcn_permlane32_swap)
  auto r = __builtin_amdgcn_permlane32_swap(a, b, false, false);
  outa = ((const int*)&r)[0];
  outb = ((const int*)&r)[1];
#else
  int bp = __shfl_xor(b, 32);
  int ap = __shfl_xor(a, 32);
  outa = (threadIdx.x & 32) ? bp : a;
  outb = (threadIdx.x & 32) ? b : ap;
#endif
}

DEVI float halfmax(float x) {
  int o0, o1;
  pl32swap(__float_as_int(x), __float_as_int(x), o0, o1);
  return fmaxf(__int_as_float(o0), __int_as_float(o1));
}
DEVI float halfsum(float x) {
  int o0, o1;
  pl32swap(__float_as_int(x), __float_as_int(x), o0, o1);
  return __int_as_float(o0) + __int_as_float(o1);
}

// ------------------------------------------------------------------
// RoPE tables: ct/st[s][j], s<2048, j<32 (f32)
// ------------------------------------------------------------------
__global__ void rope_table_kernel(float* __restrict__ ct, float* __restrict__ st) {
  int i = blockIdx.x * 256 + threadIdx.x;     // 65536 total
  int s = i >> 5, j = i & 31;
  float inv = powf(10000.0f, -(float)j * (1.0f / 32.0f));
  float a = (float)s * inv;
  ct[i] = cosf(a);
  st[i] = sinf(a);
}

// ------------------------------------------------------------------
// x f32 -> bf16 (vectorized)
// ------------------------------------------------------------------
__global__ void cvt_x_kernel(const float* __restrict__ x, unsigned short* __restrict__ xb) {
  int i = blockIdx.x * 256 + threadIdx.x;     // n/4 threads
  float4 v = ((const float4*)x)[i];
  ushort4 o;
  o.x = f2b(v.x); o.y = f2b(v.y); o.z = f2b(v.z); o.w = f2b(v.w);
  ((ushort4*)xb)[i] = o;
}

// ------------------------------------------------------------------
// W [K][N] f32  ->  WT [N][K] bf16  (LDS 32x32 tile transpose)
// ------------------------------------------------------------------
__global__ void transpose_kernel(const float* __restrict__ W, unsigned short* __restrict__ WT,
                                 int K, int N) {
  __shared__ float tile[32][33];
  int n0 = blockIdx.x * 32, k0 = blockIdx.y * 32;
  int tx = threadIdx.x, ty = threadIdx.y;     // 32 x 8
#pragma unroll
  for (int i = 0; i < 32; i += 8)
    tile[ty + i][tx] = W[(size_t)(k0 + ty + i) * N + n0 + tx];
  __syncthreads();
#pragma unroll
  for (int i = 0; i < 32; i += 8)
    WT[(size_t)(n0 + ty + i) * K + k0 + tx] = f2b(tile[tx][ty + i]);
}

// ------------------------------------------------------------------
// Shared GEMM main loop: C[128x128] tile, A [M][1024] bf16, B^T [N][1024] bf16
// 4 waves (2x2), each 64x64 via 4x4 frags of 16x16x32 MFMA, BK=64
// ------------------------------------------------------------------
DEVI void gemm_mainloop(const unsigned short* __restrict__ A, const unsigned short* __restrict__ B,
                        unsigned short* As, unsigned short* Bs,
                        int m0, int n0, int lane, int wid, int wr, int wc,
                        f32x4 acc[4][4]) {
  const int srow = lane >> 3;
  const int scol = (lane & 7) * 8;
  for (int k0 = 0; k0 < 1024; k0 += 64) {
#pragma unroll
    for (int i = 0; i < 4; ++i) {
      const int c = i * 4 + wid;
      const int row = c * 8 + srow;
      gload16(A + (size_t)(m0 + row) * 1024 + k0 + scol, (char*)As + c * 1024);
      gload16(B + (size_t)(n0 + row) * 1024 + k0 + scol, (char*)Bs + c * 1024);
    }
    __syncthreads();
#pragma unroll
    for (int kk = 0; kk < 64; kk += 32) {
      bf16x8 a[4], b[4];
#pragma unroll
      for (int mi = 0; mi < 4; ++mi)
        a[mi] = *(const bf16x8*)&As[(wr * 64 + mi * 16 + (lane & 15)) * 64 + kk + (lane >> 4) * 8];
#pragma unroll
      for (int ni = 0; ni < 4; ++ni)
        b[ni] = *(const bf16x8*)&Bs[(wc * 64 + ni * 16 + (lane & 15)) * 64 + kk + (lane >> 4) * 8];
#pragma unroll
      for (int mi = 0; mi < 4; ++mi)
#pragma unroll
        for (int ni = 0; ni < 4; ++ni)
          acc[mi][ni] = __builtin_amdgcn_mfma_f32_16x16x32_bf16(a[mi], b[ni], acc[mi][ni], 0, 0, 0);
    }
    __syncthreads();
  }
}

// ------------------------------------------------------------------
// GEMM1: qkv = Xb @ WqT^T with fused RoPE; scatter Q[B,H,S,64] K[B,H,S,64] VT[B,H,64,S]
// grid (24, 32)
// ------------------------------------------------------------------
__global__ __launch_bounds__(256) void gemm_qkv_kernel(
    const unsigned short* __restrict__ Xb, const unsigned short* __restrict__ WT,
    const float* __restrict__ ct, const float* __restrict__ st,
    unsigned short* __restrict__ Qb, unsigned short* __restrict__ Kb,
    unsigned short* __restrict__ VTb) {
  __shared__ unsigned short As[128 * 64];
  __shared__ unsigned short Bs[128 * 64];
  const int lane = threadIdx.x & 63, wid = threadIdx.x >> 6;
  const int m0 = blockIdx.y * 128, n0 = blockIdx.x * 128;
  const int wr = wid >> 1, wc = wid & 1;
  f32x4 acc[4][4] = {};
  gemm_mainloop(Xb, WT, As, Bs, m0, n0, lane, wid, wr, wc, acc);

  // wave covers exactly one head: n in [n_base, n_base+64)
  const int n_base = n0 + wc * 64;
  const int t = n_base >> 10;                 // 0=q 1=k 2=v
  const int h = (n_base & 1023) >> 6;
  if (t < 2) {
    unsigned short* dst = (t == 0) ? Qb : Kb;
#pragma unroll
    for (int mi = 0; mi < 4; ++mi) {
      const int mrow = m0 + wr * 64 + mi * 16 + ((lane >> 4) << 2);
#pragma unroll
      for (int r = 0; r < 4; ++r) {
        const int m = mrow + r;
        const int s = m & 2047, bb = m >> 11;
        const size_t base = ((size_t)(bb * 16 + h) * 2048 + s) * 64;
#pragma unroll
        for (int ni = 0; ni < 2; ++ni) {
          const int j = ni * 16 + (lane & 15);
          const float c = ct[s * 32 + j], sn = st[s * 32 + j];
          const float x1 = acc[mi][ni][r], x2 = acc[mi][ni + 2][r];
          dst[base + j]      = f2b(x1 * c + x2 * sn);
          dst[base + j + 32] = f2b(-x1 * sn + x2 * c);
        }
      }
    }
  } else {
#pragma unroll
    for (int mi = 0; mi < 4; ++mi) {
      const int mrow = m0 + wr * 64 + mi * 16 + ((lane >> 4) << 2);
      const int s = mrow & 2047, bb = mrow >> 11;
#pragma unroll
      for (int ni = 0; ni < 4; ++ni) {
        const int d = ni * 16 + (lane & 15);
        ushort4 o;
        o.x = f2b(acc[mi][ni][0]); o.y = f2b(acc[mi][ni][1]);
        o.z = f2b(acc[mi][ni][2]); o.w = f2b(acc[mi][ni][3]);
        *(ushort4*)&VTb[((size_t)(bb * 16 + h) * 64 + d) * 2048 + s] = o;
      }
    }
  }
}

// ------------------------------------------------------------------
// Flash attention v3 (causal). grid (32, 16): x = bh (XCD-clustered: flat&7 = bh&7),
// y -> jblk balanced so the two blocks sharing a CU (flat, flat+256) have
// jblk sums == 15 -> every CU gets 260 k-steps of work (was 148..372).
// Per wave: 32 q rows via 32x32x16 MFMA, swapped operands (softmax lane-local),
// explicit double-buffered K/V register prefetch, permlane half-reductions,
// defer-max rescale. No LDS, no barriers.
// ------------------------------------------------------------------
struct KVregs { bf16x8 k0, k1, k2, k3, v00, v01, v10, v11; };

DEVI void load_kv(KVregs& R, const unsigned short* __restrict__ Kh,
                  const unsigned short* __restrict__ Vh, int kbase, int ln, int hi) {
  const unsigned short* kp = Kh + (size_t)(kbase + ln) * 64 + hi * 8;
  R.k0 = *(const bf16x8*)kp;
  R.k1 = *(const bf16x8*)(kp + 16);
  R.k2 = *(const bf16x8*)(kp + 32);
  R.k3 = *(const bf16x8*)(kp + 48);
  const unsigned short* vp = Vh + (size_t)ln * 2048 + kbase + hi * 8;
  R.v00 = *(const bf16x8*)vp;
  R.v01 = *(const bf16x8*)(vp + 16);
  R.v10 = *(const bf16x8*)(vp + 32 * 2048);
  R.v11 = *(const bf16x8*)(vp + 32 * 2048 + 16);
}

template <bool DIAG>
DEVI void attn_step(const KVregs& R, const bf16x8 qf[4], int kbase, int qg, int hi,
                    float& m2, float& l_run, f32x16& acc0, f32x16& acc1) {
  const float C = 0.125f * 1.44269504f;     // scale * log2(e)
  f32x16 stv = {};
  __builtin_amdgcn_s_setprio(1);
  stv = __builtin_amdgcn_mfma_f32_32x32x16_bf16(R.k0, qf[0], stv, 0, 0, 0);
  stv = __builtin_amdgcn_mfma_f32_32x32x16_bf16(R.k1, qf[1], stv, 0, 0, 0);
  stv = __builtin_amdgcn_mfma_f32_32x32x16_bf16(R.k2, qf[2], stv, 0, 0, 0);
  stv = __builtin_amdgcn_mfma_f32_32x32x16_bf16(R.k3, qf[3], stv, 0, 0, 0);
  __builtin_amdgcn_s_setprio(0);

  // lane holds S^T[key = kbase+(r&3)+8*(r>>2)+4*hi][q], in log2 domain
  float p[16];
  float mloc = -1e30f;
#pragma unroll
  for (int r = 0; r < 16; ++r) {
    float v = stv[r] * C;
    if constexpr (DIAG) {
      const int kg = kbase + (r & 3) + ((r >> 2) << 3) + (hi << 2);
      v = (kg <= qg) ? v : -1e30f;
    }
    p[r] = v;
    mloc = fmaxf(mloc, v);
  }
  mloc = halfmax(mloc);
  // defer-max: only rescale acc when max grew by >8 nats (11.54 in log2)
  if (__any(mloc > m2 + 11.5416f)) {
    const float mnew = fmaxf(m2, mloc);
    const float sc = exp2f(m2 - mnew);
    l_run *= sc;
#pragma unroll
    for (int r = 0; r < 16; ++r) { acc0[r] *= sc; acc1[r] *= sc; }
    m2 = mnew;
  }
  float ps = 0.f;
#pragma unroll
  for (int r = 0; r < 16; ++r) { p[r] = exp2f(p[r] - m2); ps += p[r]; }
  l_run += halfsum(ps);

  // P^T -> bf16 fragments (B-operand: n=q, k=key_local=hi*8+j)
  int cw[8];
#pragma unroll
  for (int i = 0; i < 8; ++i)
    asm("v_cvt_pk_bf16_f32 %0, %1, %2" : "=v"(cw[i]) : "v"(p[2 * i]), "v"(p[2 * i + 1]));
  int a0, a1, b0, b1, a2, a3, b2, b3;
  pl32swap(cw[0], cw[2], a0, b0);   // slice 0 (keys kbase+0..15)
  pl32swap(cw[1], cw[3], a1, b1);
  pl32swap(cw[4], cw[6], a2, b2);   // slice 1 (keys kbase+16..31)
  pl32swap(cw[5], cw[7], a3, b3);
  const bf16x8 pa0 = __builtin_bit_cast(bf16x8, (i32x4){a0, a1, b0, b1});
  const bf16x8 pa1 = __builtin_bit_cast(bf16x8, (i32x4){a2, a3, b2, b3});

  __builtin_amdgcn_s_setprio(1);
  acc0 = __builtin_amdgcn_mfma_f32_32x32x16_bf16(R.v00, pa0, acc0, 0, 0, 0);
  acc0 = __builtin_amdgcn_mfma_f32_32x32x16_bf16(R.v01, pa1, acc0, 0, 0, 0);
  acc1 = __builtin_amdgcn_mfma_f32_32x32x16_bf16(R.v10, pa0, acc1, 0, 0, 0);
  acc1 = __builtin_amdgcn_mfma_f32_32x32x16_bf16(R.v11, pa1, acc1, 0, 0, 0);
  __builtin_amdgcn_s_setprio(0);
}

__global__ __launch_bounds__(256) void attn_kernel(
    const unsigned short* __restrict__ Qb, const unsigned short* __restrict__ Kb,
    const unsigned short* __restrict__ VTb, unsigned short* __restrict__ Ob) {
  const int lane = threadIdx.x & 63, wid = threadIdx.x >> 6;
  const int ln = lane & 31, hi = lane >> 5;
  const int bh = blockIdx.x;
  const int y = blockIdx.y;
  const int jblk = (y < 8) ? (15 - y) : (y - 8);  // CU-pair balanced (sum=15)
  const int q0 = jblk * 128 + wid * 32;
  const unsigned short* Qh = Qb + (size_t)bh * 2048 * 64;
  const unsigned short* Kh = Kb + (size_t)bh * 2048 * 64;
  const unsigned short* Vh = VTb + (size_t)bh * 64 * 2048;

  // Q fragments (B-operand: n=q=ln, k=d=t*16+hi*8+j)
  bf16x8 qf[4];
  {
    const unsigned short* p = Qh + (size_t)(q0 + ln) * 64 + hi * 8;
#pragma unroll
    for (int t = 0; t < 4; ++t) qf[t] = *(const bf16x8*)(p + t * 16);
  }

  f32x16 acc0 = {}, acc1 = {};
  float m2 = -1e30f, l_run = 0.f;           // log2-domain running max / denom
  const int qg = q0 + ln;
  const int ntiles = q0 / 32 + 1;

  KVregs R0, R1;
  load_kv(R0, Kh, Vh, 0, ln, hi);
  int t = 0;
  while (t + 2 < ntiles) {                  // steady state: compute t, prefetch t+1/t+2
    load_kv(R1, Kh, Vh, (t + 1) * 32, ln, hi);
    attn_step<false>(R0, qf, t * 32, qg, hi, m2, l_run, acc0, acc1);
    load_kv(R0, Kh, Vh, (t + 2) * 32, ln, hi);
    attn_step<false>(R1, qf, (t + 1) * 32, qg, hi, m2, l_run, acc0, acc1);
    t += 2;
  }
  if (t + 2 == ntiles) {                    // two left: t (R0), t+1 = diag
    load_kv(R1, Kh, Vh, (t + 1) * 32, ln, hi);
    attn_step<false>(R0, qf, t * 32, qg, hi, m2, l_run, acc0, acc1);
    attn_step<true>(R1, qf, (t + 1) * 32, qg, hi, m2, l_run, acc0, acc1);
  } else {                                  // one left: t = diag (R0)
    attn_step<true>(R0, qf, t * 32, qg, hi, m2, l_run, acc0, acc1);
  }

  // O^T: lane holds O[q][d = dt*32 + (r&3)+8*(r>>2)+4*hi]
  const float il = 1.0f / l_run;
  const int b = bh >> 4, h = bh & 15;
  unsigned short* ob = Ob + ((size_t)(b * 2048 + qg)) * 1024 + h * 64;
#pragma unroll
  for (int g = 0; g < 4; ++g) {
    ushort4 o0, o1;
    o0.x = f2b(acc0[4 * g + 0] * il); o0.y = f2b(acc0[4 * g + 1] * il);
    o0.z = f2b(acc0[4 * g + 2] * il); o0.w = f2b(acc0[4 * g + 3] * il);
    o1.x = f2b(acc1[4 * g + 0] * il); o1.y = f2b(acc1[4 * g + 1] * il);
    o1.z = f2b(acc1[4 * g + 2] * il); o1.w = f2b(acc1[4 * g + 3] * il);
    *(ushort4*)&ob[8 * g + 4 * hi]      = o0;   // dt=0
    *(ushort4*)&ob[32 + 8 * g + 4 * hi] = o1;   // dt=1
  }
}

// ------------------------------------------------------------------
// GEMM2: out = Ob @ WoT^T, f32 epilogue. grid (8, 32)
// ------------------------------------------------------------------
__global__ __launch_bounds__(256) void gemm_out_kernel(
    const unsigned short* __restrict__ Ob, const unsigned short* __restrict__ WoT,
    float* __restrict__ out) {
  __shared__ unsigned short As[128 * 64];
  __shared__ unsigned short Bs[128 * 64];
  const int lane = threadIdx.x & 63, wid = threadIdx.x >> 6;
  const int m0 = blockIdx.y * 128, n0 = blockIdx.x * 128;
  const int wr = wid >> 1, wc = wid & 1;
  f32x4 acc[4][4] = {};
  gemm_mainloop(Ob, WoT, As, Bs, m0, n0, lane, wid, wr, wc, acc);
#pragma unroll
  for (int mi = 0; mi < 4; ++mi) {
    const int mrow = m0 + wr * 64 + mi * 16 + ((lane >> 4) << 2);
#pragma unroll
    for (int ni = 0; ni < 4; ++ni) {
      const int n = n0 + wc * 64 + ni * 16 + (lane & 15);
#pragma unroll
      for (int r = 0; r < 4; ++r)
        out[(size_t)(mrow + r) * 1024 + n] = acc[mi][ni][r];
    }
  }
}

// ------------------------------------------------------------------
extern "C" void kernel_launch(void* const* d_in, const int* in_sizes, int n_in,
                              void* d_out, int out_size, void* d_ws, size_t ws_size,
                              hipStream_t stream) {
  const float* x     = (const float*)d_in[0];
  const float* w_qkv = (const float*)d_in[1];
  const float* w_o   = (const float*)d_in[2];
  float* out = (float*)d_out;
  char* ws = (char*)d_ws;

  const size_t MB = 1 << 20;
  float* ct = (float*)(ws);                          // 256 KB
  float* st = (float*)(ws + (256 << 10));            // 256 KB
  unsigned short* Xb  = (unsigned short*)(ws + (512 << 10));            // 8 MB  (reused as Ob)
  unsigned short* WqT = (unsigned short*)(ws + (512 << 10) + 8  * MB);  // 6 MB
  unsigned short* WoT = (unsigned short*)(ws + (512 << 10) + 14 * MB);  // 2 MB
  unsigned short* Qb  = (unsigned short*)(ws + (512 << 10) + 16 * MB);  // 8 MB
  unsigned short* Kb  = (unsigned short*)(ws + (512 << 10) + 24 * MB);  // 8 MB
  unsigned short* VTb = (unsigned short*)(ws + (512 << 10) + 32 * MB);  // 8 MB
  unsigned short* Ob  = Xb;  // Xb dead after gemm1; total ws = 40.5 MB

  rope_table_kernel<<<dim3(256), dim3(256), 0, stream>>>(ct, st);
  cvt_x_kernel<<<dim3(4096), dim3(256), 0, stream>>>(x, Xb);
  transpose_kernel<<<dim3(96, 32), dim3(32, 8), 0, stream>>>(w_qkv, WqT, 1024, 3072);
  transpose_kernel<<<dim3(32, 32), dim3(32, 8), 0, stream>>>(w_o, WoT, 1024, 1024);
  gemm_qkv_kernel<<<dim3(24, 32), dim3(256), 0, stream>>>(Xb, WqT, ct, st, Qb, Kb, VTb);
  attn_kernel<<<dim3(32, 16), dim3(256), 0, stream>>>(Qb, Kb, VTb, Ob);
  gemm_out_kernel<<<dim3(8, 32), dim3(256), 0, stream>>>(Ob, WoT, out);
}

// Round 4
// 155.882 us; speedup vs baseline: 1.7811x; 1.0431x over previous
//
#include <hip/hip_runtime.h>

typedef short bf16x8 __attribute__((ext_vector_type(8)));
typedef short bf16x4 __attribute__((ext_vector_type(4)));
typedef float f32x4 __attribute__((ext_vector_type(4)));
typedef float f32x16 __attribute__((ext_vector_type(16)));
typedef int i32x4 __attribute__((ext_vector_type(4)));

#define DEVI static __device__ __forceinline__

// f32 -> bf16 round-to-nearest-even
DEVI unsigned short f2b(float f) {
  unsigned u = __float_as_uint(f);
  u += 0x7FFFu + ((u >> 16) & 1u);
  return (unsigned short)(u >> 16);
}

DEVI void gload16(const void* g, void* l) {
  __builtin_amdgcn_global_load_lds((const __attribute__((address_space(1))) void*)g,
                                   (__attribute__((address_space(3))) void*)l, 16, 0, 0);
}

// permlane32_swap: outa = {a.row0, b.row0}, outb = {a.row1, b.row1}
DEVI void pl32swap(int a, int b, int& outa, int& outb) {
#if __has_builtin(__builtin_amdgcn_permlane32_swap)
  auto r = __builtin_amdgcn_permlane32_swap(a, b, false, false);
  outa = ((const int*)&r)[0];
  outb = ((const int*)&r)[1];
#else
  int bp = __shfl_xor(b, 32);
  int ap = __shfl_xor(a, 32);
  outa = (threadIdx.x & 32) ? bp : a;
  outb = (threadIdx.x & 32) ? b : ap;
#endif
}

DEVI float halfmax(float x) {
  int o0, o1;
  pl32swap(__float_as_int(x), __float_as_int(x), o0, o1);
  return fmaxf(__int_as_float(o0), __int_as_float(o1));
}
DEVI float halfsum(float x) {
  int o0, o1;
  pl32swap(__float_as_int(x), __float_as_int(x), o0, o1);
  return __int_as_float(o0) + __int_as_float(o1);
}

// ------------------------------------------------------------------
// RoPE tables: ct/st[s][j], s<2048, j<32 (f32)
// ------------------------------------------------------------------
__global__ void rope_table_kernel(float* __restrict__ ct, float* __restrict__ st) {
  int i = blockIdx.x * 256 + threadIdx.x;     // 65536 total
  int s = i >> 5, j = i & 31;
  float inv = powf(10000.0f, -(float)j * (1.0f / 32.0f));
  float a = (float)s * inv;
  ct[i] = cosf(a);
  st[i] = sinf(a);
}

// ------------------------------------------------------------------
// x f32 -> bf16 (vectorized)
// ------------------------------------------------------------------
__global__ void cvt_x_kernel(const float* __restrict__ x, unsigned short* __restrict__ xb) {
  int i = blockIdx.x * 256 + threadIdx.x;     // n/4 threads
  float4 v = ((const float4*)x)[i];
  ushort4 o;
  o.x = f2b(v.x); o.y = f2b(v.y); o.z = f2b(v.z); o.w = f2b(v.w);
  ((ushort4*)xb)[i] = o;
}

// ------------------------------------------------------------------
// W [K][N] f32  ->  WT [N][K] bf16  (LDS 32x32 tile transpose)
// ------------------------------------------------------------------
__global__ void transpose_kernel(const float* __restrict__ W, unsigned short* __restrict__ WT,
                                 int K, int N) {
  __shared__ float tile[32][33];
  int n0 = blockIdx.x * 32, k0 = blockIdx.y * 32;
  int tx = threadIdx.x, ty = threadIdx.y;     // 32 x 8
#pragma unroll
  for (int i = 0; i < 32; i += 8)
    tile[ty + i][tx] = W[(size_t)(k0 + ty + i) * N + n0 + tx];
  __syncthreads();
#pragma unroll
  for (int i = 0; i < 32; i += 8)
    WT[(size_t)(n0 + ty + i) * K + k0 + tx] = f2b(tile[tx][ty + i]);
}

// ------------------------------------------------------------------
// Shared GEMM main loop: C[128x128] tile, A [M][1024] bf16, B^T [N][1024] bf16
// 4 waves (2x2), each 64x64 via 4x4 frags of 16x16x32 MFMA, BK=64
// ------------------------------------------------------------------
DEVI void gemm_mainloop(const unsigned short* __restrict__ A, const unsigned short* __restrict__ B,
                        unsigned short* As, unsigned short* Bs,
                        int m0, int n0, int lane, int wid, int wr, int wc,
                        f32x4 acc[4][4]) {
  const int srow = lane >> 3;
  const int scol = (lane & 7) * 8;
  for (int k0 = 0; k0 < 1024; k0 += 64) {
#pragma unroll
    for (int i = 0; i < 4; ++i) {
      const int c = i * 4 + wid;
      const int row = c * 8 + srow;
      gload16(A + (size_t)(m0 + row) * 1024 + k0 + scol, (char*)As + c * 1024);
      gload16(B + (size_t)(n0 + row) * 1024 + k0 + scol, (char*)Bs + c * 1024);
    }
    __syncthreads();
#pragma unroll
    for (int kk = 0; kk < 64; kk += 32) {
      bf16x8 a[4], b[4];
#pragma unroll
      for (int mi = 0; mi < 4; ++mi)
        a[mi] = *(const bf16x8*)&As[(wr * 64 + mi * 16 + (lane & 15)) * 64 + kk + (lane >> 4) * 8];
#pragma unroll
      for (int ni = 0; ni < 4; ++ni)
        b[ni] = *(const bf16x8*)&Bs[(wc * 64 + ni * 16 + (lane & 15)) * 64 + kk + (lane >> 4) * 8];
#pragma unroll
      for (int mi = 0; mi < 4; ++mi)
#pragma unroll
        for (int ni = 0; ni < 4; ++ni)
          acc[mi][ni] = __builtin_amdgcn_mfma_f32_16x16x32_bf16(a[mi], b[ni], acc[mi][ni], 0, 0, 0);
    }
    __syncthreads();
  }
}

// ------------------------------------------------------------------
// GEMM1: qkv = Xb @ WqT^T with fused RoPE; scatter Q[B,H,S,64] K[B,H,S,64] VT[B,H,64,S]
// grid (24, 32)
// ------------------------------------------------------------------
__global__ __launch_bounds__(256) void gemm_qkv_kernel(
    const unsigned short* __restrict__ Xb, const unsigned short* __restrict__ WT,
    const float* __restrict__ ct, const float* __restrict__ st,
    unsigned short* __restrict__ Qb, unsigned short* __restrict__ Kb,
    unsigned short* __restrict__ VTb) {
  __shared__ unsigned short As[128 * 64];
  __shared__ unsigned short Bs[128 * 64];
  const int lane = threadIdx.x & 63, wid = threadIdx.x >> 6;
  const int m0 = blockIdx.y * 128, n0 = blockIdx.x * 128;
  const int wr = wid >> 1, wc = wid & 1;
  f32x4 acc[4][4] = {};
  gemm_mainloop(Xb, WT, As, Bs, m0, n0, lane, wid, wr, wc, acc);

  // wave covers exactly one head: n in [n_base, n_base+64)
  const int n_base = n0 + wc * 64;
  const int t = n_base >> 10;                 // 0=q 1=k 2=v
  const int h = (n_base & 1023) >> 6;
  if (t < 2) {
    unsigned short* dst = (t == 0) ? Qb : Kb;
#pragma unroll
    for (int mi = 0; mi < 4; ++mi) {
      const int mrow = m0 + wr * 64 + mi * 16 + ((lane >> 4) << 2);
#pragma unroll
      for (int r = 0; r < 4; ++r) {
        const int m = mrow + r;
        const int s = m & 2047, bb = m >> 11;
        const size_t base = ((size_t)(bb * 16 + h) * 2048 + s) * 64;
#pragma unroll
        for (int ni = 0; ni < 2; ++ni) {
          const int j = ni * 16 + (lane & 15);
          const float c = ct[s * 32 + j], sn = st[s * 32 + j];
          const float x1 = acc[mi][ni][r], x2 = acc[mi][ni + 2][r];
          dst[base + j]      = f2b(x1 * c + x2 * sn);
          dst[base + j + 32] = f2b(-x1 * sn + x2 * c);
        }
      }
    }
  } else {
#pragma unroll
    for (int mi = 0; mi < 4; ++mi) {
      const int mrow = m0 + wr * 64 + mi * 16 + ((lane >> 4) << 2);
      const int s = mrow & 2047, bb = mrow >> 11;
#pragma unroll
      for (int ni = 0; ni < 4; ++ni) {
        const int d = ni * 16 + (lane & 15);
        ushort4 o;
        o.x = f2b(acc[mi][ni][0]); o.y = f2b(acc[mi][ni][1]);
        o.z = f2b(acc[mi][ni][2]); o.w = f2b(acc[mi][ni][3]);
        *(ushort4*)&VTb[((size_t)(bb * 16 + h) * 64 + d) * 2048 + s] = o;
      }
    }
  }
}

// ------------------------------------------------------------------
// Flash attention v4 (causal). grid (32, 16): x = bh, y -> jblk CU-pair balanced.
// Block-level LDS staging of K+V (KVBLK=64, double-buffered, XOR chunk swizzle
// c' = c ^ (row&7) applied on BOTH global source and LDS read — rule #21),
// shared by all 4 waves. Swapped-operand softmax (lane-local state),
// permlane half-reductions, defer-max. One __syncthreads per 64-key tile.
// ------------------------------------------------------------------
DEVI void stage_kv(const unsigned short* __restrict__ Kh, const unsigned short* __restrict__ Vh,
                   int kbase, unsigned char* buf, int tid) {
  const int w64 = tid & ~63;                  // wave-uniform thread base
  unsigned char* bufV = buf + 8192;
#pragma unroll
  for (int i = 0; i < 2; ++i) {               // K: 64 rows x 8 chunks of 16B
    const int T = i * 256 + tid;
    const int r = T >> 3;
    const int cc = (T & 7) ^ (r & 7);
    gload16(Kh + (size_t)(kbase + r) * 64 + cc * 8, buf + (i * 256 + w64) * 16);
  }
#pragma unroll
  for (int i = 0; i < 2; ++i) {               // V: 64 d-rows x 8 chunks of 16B
    const int T = i * 256 + tid;
    const int r = T >> 3;
    const int cc = (T & 7) ^ (r & 7);
    gload16(Vh + (size_t)r * 2048 + kbase + cc * 8, bufV + (i * 256 + w64) * 16);
  }
}

DEVI void attn_sub(const unsigned char* __restrict__ bufK, const unsigned char* __restrict__ bufV,
                   const bf16x8 qf[4], int s, int kglob, bool diag, int qg, int ln, int hi,
                   float& m2, float& l_run, f32x16& acc0, f32x16& acc1) {
  const float C = 0.125f * 1.44269504f;       // scale * log2(e)
  const int rx = ln & 7;
  // K frags (A-operand: m=key=ln within subtile, k=d)
  bf16x8 kf[4];
#pragma unroll
  for (int j = 0; j < 4; ++j) {
    const int cc = (2 * j + hi) ^ rx;
    kf[j] = *(const bf16x8*)(bufK + (s * 32 + ln) * 128 + cc * 16);
  }
  // V frags (A-operand for PV: m=d, k=key_local)
  bf16x8 v0[2], v1[2];
#pragma unroll
  for (int p = 0; p < 2; ++p) {
    const int cc = (4 * s + 2 * p + hi) ^ rx;
    v0[p] = *(const bf16x8*)(bufV + ln * 128 + cc * 16);
    v1[p] = *(const bf16x8*)(bufV + (ln + 32) * 128 + cc * 16);
  }

  f32x16 stv = {};
  __builtin_amdgcn_s_setprio(1);
  stv = __builtin_amdgcn_mfma_f32_32x32x16_bf16(kf[0], qf[0], stv, 0, 0, 0);
  stv = __builtin_amdgcn_mfma_f32_32x32x16_bf16(kf[1], qf[1], stv, 0, 0, 0);
  stv = __builtin_amdgcn_mfma_f32_32x32x16_bf16(kf[2], qf[2], stv, 0, 0, 0);
  stv = __builtin_amdgcn_mfma_f32_32x32x16_bf16(kf[3], qf[3], stv, 0, 0, 0);
  __builtin_amdgcn_s_setprio(0);

  // lane holds S^T[key = kglob+(r&3)+8*(r>>2)+4*hi][q], log2 domain
  float p[16];
  float mloc = -1e30f;
#pragma unroll
  for (int r = 0; r < 16; ++r) p[r] = stv[r] * C;
  if (diag) {
#pragma unroll
    for (int r = 0; r < 16; ++r) {
      const int kg = kglob + (r & 3) + ((r >> 2) << 3) + (hi << 2);
      if (kg > qg) p[r] = -1e30f;
    }
  }
#pragma unroll
  for (int r = 0; r < 16; ++r) mloc = fmaxf(mloc, p[r]);
  mloc = halfmax(mloc);
  // defer-max: only rescale acc when max grew by >8 nats (11.54 in log2)
  if (__any(mloc > m2 + 11.5416f)) {
    const float mnew = fmaxf(m2, mloc);
    const float sc = exp2f(m2 - mnew);
    l_run *= sc;
#pragma unroll
    for (int r = 0; r < 16; ++r) { acc0[r] *= sc; acc1[r] *= sc; }
    m2 = mnew;
  }
  float ps = 0.f;
#pragma unroll
  for (int r = 0; r < 16; ++r) { p[r] = exp2f(p[r] - m2); ps += p[r]; }
  l_run += halfsum(ps);

  // P^T -> bf16 fragments (B-operand: n=q, k=key_local=hi*8+j)
  int cw[8];
#pragma unroll
  for (int i = 0; i < 8; ++i)
    asm("v_cvt_pk_bf16_f32 %0, %1, %2" : "=v"(cw[i]) : "v"(p[2 * i]), "v"(p[2 * i + 1]));
  int a0, a1, b0, b1, a2, a3, b2, b3;
  pl32swap(cw[0], cw[2], a0, b0);   // keys kglob+0..15
  pl32swap(cw[1], cw[3], a1, b1);
  pl32swap(cw[4], cw[6], a2, b2);   // keys kglob+16..31
  pl32swap(cw[5], cw[7], a3, b3);
  const bf16x8 pa0 = __builtin_bit_cast(bf16x8, (i32x4){a0, a1, b0, b1});
  const bf16x8 pa1 = __builtin_bit_cast(bf16x8, (i32x4){a2, a3, b2, b3});

  __builtin_amdgcn_s_setprio(1);
  acc0 = __builtin_amdgcn_mfma_f32_32x32x16_bf16(v0[0], pa0, acc0, 0, 0, 0);
  acc0 = __builtin_amdgcn_mfma_f32_32x32x16_bf16(v0[1], pa1, acc0, 0, 0, 0);
  acc1 = __builtin_amdgcn_mfma_f32_32x32x16_bf16(v1[0], pa0, acc1, 0, 0, 0);
  acc1 = __builtin_amdgcn_mfma_f32_32x32x16_bf16(v1[1], pa1, acc1, 0, 0, 0);
  __builtin_amdgcn_s_setprio(0);
}

__global__ __launch_bounds__(256) void attn_kernel(
    const unsigned short* __restrict__ Qb, const unsigned short* __restrict__ Kb,
    const unsigned short* __restrict__ VTb, unsigned short* __restrict__ Ob) {
  __shared__ unsigned char smem[2][16384];    // per buffer: K 8KB | V 8KB
  const int tid = threadIdx.x;
  const int lane = tid & 63, wid = tid >> 6;
  const int ln = lane & 31, hi = lane >> 5;
  const int bh = blockIdx.x;
  const int y = blockIdx.y;
  const int jblk = (y < 8) ? (15 - y) : (y - 8);  // CU-pair balanced
  const int q0 = jblk * 128 + wid * 32;
  const unsigned short* Qh = Qb + (size_t)bh * 2048 * 64;
  const unsigned short* Kh = Kb + (size_t)bh * 2048 * 64;
  const unsigned short* Vh = VTb + (size_t)bh * 64 * 2048;

  // Q fragments (B-operand: n=q=ln, k=d=t*16+hi*8+j)
  bf16x8 qf[4];
  {
    const unsigned short* p = Qh + (size_t)(q0 + ln) * 64 + hi * 8;
#pragma unroll
    for (int t = 0; t < 4; ++t) qf[t] = *(const bf16x8*)(p + t * 16);
  }

  f32x16 acc0 = {}, acc1 = {};
  float m2 = -1e30f, l_run = 0.f;
  const int qg = q0 + ln;
  const int n32 = q0 / 32 + 1;                // 32-key subtiles this wave needs
  const int tmax = jblk * 2 + 2;              // 64-key tiles staged per block (uniform)

  stage_kv(Kh, Vh, 0, smem[0], tid);
  __syncthreads();
  for (int t = 0; t < tmax; ++t) {
    if (t + 1 < tmax) stage_kv(Kh, Vh, (t + 1) * 64, smem[(t + 1) & 1], tid);
    const unsigned char* bufK = smem[t & 1];
    const unsigned char* bufV = bufK + 8192;
#pragma unroll
    for (int s = 0; s < 2; ++s) {
      const int g32 = 2 * t + s;
      if (g32 < n32)
        attn_sub(bufK, bufV, qf, s, g32 * 32, g32 == n32 - 1, qg, ln, hi,
                 m2, l_run, acc0, acc1);
    }
    __syncthreads();
  }

  // O^T: lane holds O[q][d = dt*32 + (r&3)+8*(r>>2)+4*hi]
  const float il = 1.0f / l_run;
  const int b = bh >> 4, h = bh & 15;
  unsigned short* ob = Ob + ((size_t)(b * 2048 + qg)) * 1024 + h * 64;
#pragma unroll
  for (int g = 0; g < 4; ++g) {
    ushort4 o0, o1;
    o0.x = f2b(acc0[4 * g + 0] * il); o0.y = f2b(acc0[4 * g + 1] * il);
    o0.z = f2b(acc0[4 * g + 2] * il); o0.w = f2b(acc0[4 * g + 3] * il);
    o1.x = f2b(acc1[4 * g + 0] * il); o1.y = f2b(acc1[4 * g + 1] * il);
    o1.z = f2b(acc1[4 * g + 2] * il); o1.w = f2b(acc1[4 * g + 3] * il);
    *(ushort4*)&ob[8 * g + 4 * hi]      = o0;   // dt=0
    *(ushort4*)&ob[32 + 8 * g + 4 * hi] = o1;   // dt=1
  }
}

// ------------------------------------------------------------------
// GEMM2: out = Ob @ WoT^T, f32 epilogue. grid (8, 32)
// ------------------------------------------------------------------
__global__ __launch_bounds__(256) void gemm_out_kernel(
    const unsigned short* __restrict__ Ob, const unsigned short* __restrict__ WoT,
    float* __restrict__ out) {
  __shared__ unsigned short As[128 * 64];
  __shared__ unsigned short Bs[128 * 64];
  const int lane = threadIdx.x & 63, wid = threadIdx.x >> 6;
  const int m0 = blockIdx.y * 128, n0 = blockIdx.x * 128;
  const int wr = wid >> 1, wc = wid & 1;
  f32x4 acc[4][4] = {};
  gemm_mainloop(Ob, WoT, As, Bs, m0, n0, lane, wid, wr, wc, acc);
#pragma unroll
  for (int mi = 0; mi < 4; ++mi) {
    const int mrow = m0 + wr * 64 + mi * 16 + ((lane >> 4) << 2);
#pragma unroll
    for (int ni = 0; ni < 4; ++ni) {
      const int n = n0 + wc * 64 + ni * 16 + (lane & 15);
#pragma unroll
      for (int r = 0; r < 4; ++r)
        out[(size_t)(mrow + r) * 1024 + n] = acc[mi][ni][r];
    }
  }
}

// ------------------------------------------------------------------
extern "C" void kernel_launch(void* const* d_in, const int* in_sizes, int n_in,
                              void* d_out, int out_size, void* d_ws, size_t ws_size,
                              hipStream_t stream) {
  const float* x     = (const float*)d_in[0];
  const float* w_qkv = (const float*)d_in[1];
  const float* w_o   = (const float*)d_in[2];
  float* out = (float*)d_out;
  char* ws = (char*)d_ws;

  const size_t MB = 1 << 20;
  float* ct = (float*)(ws);                          // 256 KB
  float* st = (float*)(ws + (256 << 10));            // 256 KB
  unsigned short* Xb  = (unsigned short*)(ws + (512 << 10));            // 8 MB  (reused as Ob)
  unsigned short* WqT = (unsigned short*)(ws + (512 << 10) + 8  * MB);  // 6 MB
  unsigned short* WoT = (unsigned short*)(ws + (512 << 10) + 14 * MB);  // 2 MB
  unsigned short* Qb  = (unsigned short*)(ws + (512 << 10) + 16 * MB);  // 8 MB
  unsigned short* Kb  = (unsigned short*)(ws + (512 << 10) + 24 * MB);  // 8 MB
  unsigned short* VTb = (unsigned short*)(ws + (512 << 10) + 32 * MB);  // 8 MB
  unsigned short* Ob  = Xb;  // Xb dead after gemm1; total ws = 40.5 MB

  rope_table_kernel<<<dim3(256), dim3(256), 0, stream>>>(ct, st);
  cvt_x_kernel<<<dim3(4096), dim3(256), 0, stream>>>(x, Xb);
  transpose_kernel<<<dim3(96, 32), dim3(32, 8), 0, stream>>>(w_qkv, WqT, 1024, 3072);
  transpose_kernel<<<dim3(32, 32), dim3(32, 8), 0, stream>>>(w_o, WoT, 1024, 1024);
  gemm_qkv_kernel<<<dim3(24, 32), dim3(256), 0, stream>>>(Xb, WqT, ct, st, Qb, Kb, VTb);
  attn_kernel<<<dim3(32, 16), dim3(256), 0, stream>>>(Qb, Kb, VTb, Ob);
  gemm_out_kernel<<<dim3(8, 32), dim3(256), 0, stream>>>(Ob, WoT, out);
}

// Round 5
// 155.174 us; speedup vs baseline: 1.7893x; 1.0046x over previous
//
#include <hip/hip_runtime.h>

typedef short bf16x8 __attribute__((ext_vector_type(8)));
typedef short bf16x4 __attribute__((ext_vector_type(4)));
typedef float f32x4 __attribute__((ext_vector_type(4)));
typedef float f32x16 __attribute__((ext_vector_type(16)));
typedef int i32x4 __attribute__((ext_vector_type(4)));

#define DEVI static __device__ __forceinline__

// f32 -> bf16 round-to-nearest-even
DEVI unsigned short f2b(float f) {
  unsigned u = __float_as_uint(f);
  u += 0x7FFFu + ((u >> 16) & 1u);
  return (unsigned short)(u >> 16);
}

DEVI void gload16(const void* g, void* l) {
  __builtin_amdgcn_global_load_lds((const __attribute__((address_space(1))) void*)g,
                                   (__attribute__((address_space(3))) void*)l, 16, 0, 0);
}

// permlane32_swap: outa = {a.row0, b.row0}, outb = {a.row1, b.row1}
DEVI void pl32swap(int a, int b, int& outa, int& outb) {
#if __has_builtin(__builtin_amdgcn_permlane32_swap)
  auto r = __builtin_amdgcn_permlane32_swap(a, b, false, false);
  outa = ((const int*)&r)[0];
  outb = ((const int*)&r)[1];
#else
  int bp = __shfl_xor(b, 32);
  int ap = __shfl_xor(a, 32);
  outa = (threadIdx.x & 32) ? bp : a;
  outb = (threadIdx.x & 32) ? b : ap;
#endif
}

DEVI float halfmax(float x) {
  int o0, o1;
  pl32swap(__float_as_int(x), __float_as_int(x), o0, o1);
  return fmaxf(__int_as_float(o0), __int_as_float(o1));
}
DEVI float halfsum(float x) {
  int o0, o1;
  pl32swap(__float_as_int(x), __float_as_int(x), o0, o1);
  return __int_as_float(o0) + __int_as_float(o1);
}

// ------------------------------------------------------------------
// RoPE tables: ct/st[s][j], s<2048, j<32 (f32)
// ------------------------------------------------------------------
__global__ void rope_table_kernel(float* __restrict__ ct, float* __restrict__ st) {
  int i = blockIdx.x * 256 + threadIdx.x;     // 65536 total
  int s = i >> 5, j = i & 31;
  float inv = powf(10000.0f, -(float)j * (1.0f / 32.0f));
  float a = (float)s * inv;
  ct[i] = cosf(a);
  st[i] = sinf(a);
}

// ------------------------------------------------------------------
// x f32 -> bf16 (vectorized)
// ------------------------------------------------------------------
__global__ void cvt_x_kernel(const float* __restrict__ x, unsigned short* __restrict__ xb) {
  int i = blockIdx.x * 256 + threadIdx.x;     // n/4 threads
  float4 v = ((const float4*)x)[i];
  ushort4 o;
  o.x = f2b(v.x); o.y = f2b(v.y); o.z = f2b(v.z); o.w = f2b(v.w);
  ((ushort4*)xb)[i] = o;
}

// ------------------------------------------------------------------
// W [K][N] f32  ->  WT [N][K] bf16  (LDS 32x32 tile transpose)
// ------------------------------------------------------------------
__global__ void transpose_kernel(const float* __restrict__ W, unsigned short* __restrict__ WT,
                                 int K, int N) {
  __shared__ float tile[32][33];
  int n0 = blockIdx.x * 32, k0 = blockIdx.y * 32;
  int tx = threadIdx.x, ty = threadIdx.y;     // 32 x 8
#pragma unroll
  for (int i = 0; i < 32; i += 8)
    tile[ty + i][tx] = W[(size_t)(k0 + ty + i) * N + n0 + tx];
  __syncthreads();
#pragma unroll
  for (int i = 0; i < 32; i += 8)
    WT[(size_t)(n0 + ty + i) * K + k0 + tx] = f2b(tile[tx][ty + i]);
}

// ------------------------------------------------------------------
// Shared GEMM main loop: C[128x128] tile, A [M][1024] bf16, B^T [N][1024] bf16
// 4 waves (2x2), each 64x64 via 4x4 frags of 16x16x32 MFMA, BK=64
// ------------------------------------------------------------------
DEVI void gemm_mainloop(const unsigned short* __restrict__ A, const unsigned short* __restrict__ B,
                        unsigned short* As, unsigned short* Bs,
                        int m0, int n0, int lane, int wid, int wr, int wc,
                        f32x4 acc[4][4]) {
  const int srow = lane >> 3;
  const int scol = (lane & 7) * 8;
  for (int k0 = 0; k0 < 1024; k0 += 64) {
#pragma unroll
    for (int i = 0; i < 4; ++i) {
      const int c = i * 4 + wid;
      const int row = c * 8 + srow;
      gload16(A + (size_t)(m0 + row) * 1024 + k0 + scol, (char*)As + c * 1024);
      gload16(B + (size_t)(n0 + row) * 1024 + k0 + scol, (char*)Bs + c * 1024);
    }
    __syncthreads();
#pragma unroll
    for (int kk = 0; kk < 64; kk += 32) {
      bf16x8 a[4], b[4];
#pragma unroll
      for (int mi = 0; mi < 4; ++mi)
        a[mi] = *(const bf16x8*)&As[(wr * 64 + mi * 16 + (lane & 15)) * 64 + kk + (lane >> 4) * 8];
#pragma unroll
      for (int ni = 0; ni < 4; ++ni)
        b[ni] = *(const bf16x8*)&Bs[(wc * 64 + ni * 16 + (lane & 15)) * 64 + kk + (lane >> 4) * 8];
#pragma unroll
      for (int mi = 0; mi < 4; ++mi)
#pragma unroll
        for (int ni = 0; ni < 4; ++ni)
          acc[mi][ni] = __builtin_amdgcn_mfma_f32_16x16x32_bf16(a[mi], b[ni], acc[mi][ni], 0, 0, 0);
    }
    __syncthreads();
  }
}

// ------------------------------------------------------------------
// GEMM1: qkv = Xb @ WqT^T with fused RoPE; scatter Q[B,H,S,64] K[B,H,S,64] VT[B,H,64,S]
// grid (24, 32)
// ------------------------------------------------------------------
__global__ __launch_bounds__(256) void gemm_qkv_kernel(
    const unsigned short* __restrict__ Xb, const unsigned short* __restrict__ WT,
    const float* __restrict__ ct, const float* __restrict__ st,
    unsigned short* __restrict__ Qb, unsigned short* __restrict__ Kb,
    unsigned short* __restrict__ VTb) {
  __shared__ unsigned short As[128 * 64];
  __shared__ unsigned short Bs[128 * 64];
  const int lane = threadIdx.x & 63, wid = threadIdx.x >> 6;
  const int m0 = blockIdx.y * 128, n0 = blockIdx.x * 128;
  const int wr = wid >> 1, wc = wid & 1;
  f32x4 acc[4][4] = {};
  gemm_mainloop(Xb, WT, As, Bs, m0, n0, lane, wid, wr, wc, acc);

  // wave covers exactly one head: n in [n_base, n_base+64)
  const int n_base = n0 + wc * 64;
  const int t = n_base >> 10;                 // 0=q 1=k 2=v
  const int h = (n_base & 1023) >> 6;
  if (t < 2) {
    unsigned short* dst = (t == 0) ? Qb : Kb;
#pragma unroll
    for (int mi = 0; mi < 4; ++mi) {
      const int mrow = m0 + wr * 64 + mi * 16 + ((lane >> 4) << 2);
#pragma unroll
      for (int r = 0; r < 4; ++r) {
        const int m = mrow + r;
        const int s = m & 2047, bb = m >> 11;
        const size_t base = ((size_t)(bb * 16 + h) * 2048 + s) * 64;
#pragma unroll
        for (int ni = 0; ni < 2; ++ni) {
          const int j = ni * 16 + (lane & 15);
          const float c = ct[s * 32 + j], sn = st[s * 32 + j];
          const float x1 = acc[mi][ni][r], x2 = acc[mi][ni + 2][r];
          dst[base + j]      = f2b(x1 * c + x2 * sn);
          dst[base + j + 32] = f2b(-x1 * sn + x2 * c);
        }
      }
    }
  } else {
#pragma unroll
    for (int mi = 0; mi < 4; ++mi) {
      const int mrow = m0 + wr * 64 + mi * 16 + ((lane >> 4) << 2);
      const int s = mrow & 2047, bb = mrow >> 11;
#pragma unroll
      for (int ni = 0; ni < 4; ++ni) {
        const int d = ni * 16 + (lane & 15);
        ushort4 o;
        o.x = f2b(acc[mi][ni][0]); o.y = f2b(acc[mi][ni][1]);
        o.z = f2b(acc[mi][ni][2]); o.w = f2b(acc[mi][ni][3]);
        *(ushort4*)&VTb[((size_t)(bb * 16 + h) * 64 + d) * 2048 + s] = o;
      }
    }
  }
}

// ------------------------------------------------------------------
// Flash attention v5 (causal). grid (32 bh, 8 p), 512 threads (8 waves).
// UNIFORM-WORK blocks: waves 0-3 handle q-tile jA=15-p, waves 4-7 handle jB=p
// -> every block executes exactly 260 32-key subtiles (makespan independent
// of dispatch->CU mapping, which round 4 showed we cannot assume).
// Block-level LDS staging of K+V (KVBLK=64, double-buffered, XOR chunk
// swizzle both-sides), shared by all 8 waves. Swapped-operand softmax
// (lane-local state), permlane half-reductions, defer-max.
// ------------------------------------------------------------------
DEVI void stage_kv(const unsigned short* __restrict__ Kh, const unsigned short* __restrict__ Vh,
                   int kbase, unsigned char* buf, int tid) {
  const int w64 = tid & ~63;                  // wave-uniform thread base
  unsigned char* bufV = buf + 8192;
  // K: 64 rows x 8 chunks of 16B (512 chunks, 1 per thread)
  {
    const int r = tid >> 3;
    const int cc = (tid & 7) ^ (r & 7);
    gload16(Kh + (size_t)(kbase + r) * 64 + cc * 8, buf + w64 * 16);
  }
  // V: 64 d-rows x 8 chunks of 16B
  {
    const int r = tid >> 3;
    const int cc = (tid & 7) ^ (r & 7);
    gload16(Vh + (size_t)r * 2048 + kbase + cc * 8, bufV + w64 * 16);
  }
}

DEVI void attn_sub(const unsigned char* __restrict__ bufK, const unsigned char* __restrict__ bufV,
                   const bf16x8 qf[4], int s, int kglob, bool diag, int qg, int ln, int hi,
                   float& m2, float& l_run, f32x16& acc0, f32x16& acc1) {
  const float C = 0.125f * 1.44269504f;       // scale * log2(e)
  const int rx = ln & 7;
  // K frags (A-operand: m=key=ln within subtile, k=d)
  bf16x8 kf[4];
#pragma unroll
  for (int j = 0; j < 4; ++j) {
    const int cc = (2 * j + hi) ^ rx;
    kf[j] = *(const bf16x8*)(bufK + (s * 32 + ln) * 128 + cc * 16);
  }
  // V frags (A-operand for PV: m=d, k=key_local)
  bf16x8 v0[2], v1[2];
#pragma unroll
  for (int p = 0; p < 2; ++p) {
    const int cc = (4 * s + 2 * p + hi) ^ rx;
    v0[p] = *(const bf16x8*)(bufV + ln * 128 + cc * 16);
    v1[p] = *(const bf16x8*)(bufV + (ln + 32) * 128 + cc * 16);
  }

  f32x16 stv = {};
  __builtin_amdgcn_s_setprio(1);
  stv = __builtin_amdgcn_mfma_f32_32x32x16_bf16(kf[0], qf[0], stv, 0, 0, 0);
  stv = __builtin_amdgcn_mfma_f32_32x32x16_bf16(kf[1], qf[1], stv, 0, 0, 0);
  stv = __builtin_amdgcn_mfma_f32_32x32x16_bf16(kf[2], qf[2], stv, 0, 0, 0);
  stv = __builtin_amdgcn_mfma_f32_32x32x16_bf16(kf[3], qf[3], stv, 0, 0, 0);
  __builtin_amdgcn_s_setprio(0);

  // lane holds S^T[key = kglob+(r&3)+8*(r>>2)+4*hi][q], log2 domain
  float p[16];
  float mloc = -1e30f;
#pragma unroll
  for (int r = 0; r < 16; ++r) p[r] = stv[r] * C;
  if (diag) {
#pragma unroll
    for (int r = 0; r < 16; ++r) {
      const int kg = kglob + (r & 3) + ((r >> 2) << 3) + (hi << 2);
      if (kg > qg) p[r] = -1e30f;
    }
  }
#pragma unroll
  for (int r = 0; r < 16; ++r) mloc = fmaxf(mloc, p[r]);
  mloc = halfmax(mloc);
  // defer-max: only rescale acc when max grew by >8 nats (11.54 in log2)
  if (__any(mloc > m2 + 11.5416f)) {
    const float mnew = fmaxf(m2, mloc);
    const float sc = exp2f(m2 - mnew);
    l_run *= sc;
#pragma unroll
    for (int r = 0; r < 16; ++r) { acc0[r] *= sc; acc1[r] *= sc; }
    m2 = mnew;
  }
  float ps = 0.f;
#pragma unroll
  for (int r = 0; r < 16; ++r) { p[r] = exp2f(p[r] - m2); ps += p[r]; }
  l_run += halfsum(ps);

  // P^T -> bf16 fragments (B-operand: n=q, k=key_local=hi*8+j)
  int cw[8];
#pragma unroll
  for (int i = 0; i < 8; ++i)
    asm("v_cvt_pk_bf16_f32 %0, %1, %2" : "=v"(cw[i]) : "v"(p[2 * i]), "v"(p[2 * i + 1]));
  int a0, a1, b0, b1, a2, a3, b2, b3;
  pl32swap(cw[0], cw[2], a0, b0);   // keys kglob+0..15
  pl32swap(cw[1], cw[3], a1, b1);
  pl32swap(cw[4], cw[6], a2, b2);   // keys kglob+16..31
  pl32swap(cw[5], cw[7], a3, b3);
  const bf16x8 pa0 = __builtin_bit_cast(bf16x8, (i32x4){a0, a1, b0, b1});
  const bf16x8 pa1 = __builtin_bit_cast(bf16x8, (i32x4){a2, a3, b2, b3});

  __builtin_amdgcn_s_setprio(1);
  acc0 = __builtin_amdgcn_mfma_f32_32x32x16_bf16(v0[0], pa0, acc0, 0, 0, 0);
  acc0 = __builtin_amdgcn_mfma_f32_32x32x16_bf16(v0[1], pa1, acc0, 0, 0, 0);
  acc1 = __builtin_amdgcn_mfma_f32_32x32x16_bf16(v1[0], pa0, acc1, 0, 0, 0);
  acc1 = __builtin_amdgcn_mfma_f32_32x32x16_bf16(v1[1], pa1, acc1, 0, 0, 0);
  __builtin_amdgcn_s_setprio(0);
}

__global__ __launch_bounds__(512) void attn_kernel(
    const unsigned short* __restrict__ Qb, const unsigned short* __restrict__ Kb,
    const unsigned short* __restrict__ VTb, unsigned short* __restrict__ Ob) {
  __shared__ unsigned char smem[2][16384];    // per buffer: K 8KB | V 8KB
  const int tid = threadIdx.x;
  const int lane = tid & 63, wid = tid >> 6;
  const int ln = lane & 31, hi = lane >> 5;
  const int bh = blockIdx.x;
  const int p = blockIdx.y;
  const int jA = 15 - p;                      // heavy q-tile (waves 0-3)
  const int j = (wid < 4) ? jA : p;           // SIMD s hosts wid s (heavy) + s+4 (light)
  const int q0 = j * 128 + (wid & 3) * 32;
  const unsigned short* Qh = Qb + (size_t)bh * 2048 * 64;
  const unsigned short* Kh = Kb + (size_t)bh * 2048 * 64;
  const unsigned short* Vh = VTb + (size_t)bh * 64 * 2048;

  // Q fragments (B-operand: n=q=ln, k=d=t*16+hi*8+j)
  bf16x8 qf[4];
  {
    const unsigned short* pq = Qh + (size_t)(q0 + ln) * 64 + hi * 8;
#pragma unroll
    for (int t = 0; t < 4; ++t) qf[t] = *(const bf16x8*)(pq + t * 16);
  }

  f32x16 acc0 = {}, acc1 = {};
  float m2 = -1e30f, l_run = 0.f;
  const int qg = q0 + ln;
  const int n32 = q0 / 32 + 1;                // 32-key subtiles this wave needs
  const int tmax = jA * 2 + 2;                // 64-key tiles staged (heavy need)

  stage_kv(Kh, Vh, 0, smem[0], tid);
  __syncthreads();
  for (int t = 0; t < tmax; ++t) {
    if (t + 1 < tmax) stage_kv(Kh, Vh, (t + 1) * 64, smem[(t + 1) & 1], tid);
    const unsigned char* bufK = smem[t & 1];
    const unsigned char* bufV = bufK + 8192;
#pragma unroll
    for (int s = 0; s < 2; ++s) {
      const int g32 = 2 * t + s;
      if (g32 < n32)
        attn_sub(bufK, bufV, qf, s, g32 * 32, g32 == n32 - 1, qg, ln, hi,
                 m2, l_run, acc0, acc1);
    }
    __syncthreads();
  }

  // O^T: lane holds O[q][d = dt*32 + (r&3)+8*(r>>2)+4*hi]
  const float il = 1.0f / l_run;
  const int b = bh >> 4, h = bh & 15;
  unsigned short* ob = Ob + ((size_t)(b * 2048 + qg)) * 1024 + h * 64;
#pragma unroll
  for (int g = 0; g < 4; ++g) {
    ushort4 o0, o1;
    o0.x = f2b(acc0[4 * g + 0] * il); o0.y = f2b(acc0[4 * g + 1] * il);
    o0.z = f2b(acc0[4 * g + 2] * il); o0.w = f2b(acc0[4 * g + 3] * il);
    o1.x = f2b(acc1[4 * g + 0] * il); o1.y = f2b(acc1[4 * g + 1] * il);
    o1.z = f2b(acc1[4 * g + 2] * il); o1.w = f2b(acc1[4 * g + 3] * il);
    *(ushort4*)&ob[8 * g + 4 * hi]      = o0;   // dt=0
    *(ushort4*)&ob[32 + 8 * g + 4 * hi] = o1;   // dt=1
  }
}

// ------------------------------------------------------------------
// GEMM2: out = Ob @ WoT^T, f32 epilogue. grid (8, 32)
// ------------------------------------------------------------------
__global__ __launch_bounds__(256) void gemm_out_kernel(
    const unsigned short* __restrict__ Ob, const unsigned short* __restrict__ WoT,
    float* __restrict__ out) {
  __shared__ unsigned short As[128 * 64];
  __shared__ unsigned short Bs[128 * 64];
  const int lane = threadIdx.x & 63, wid = threadIdx.x >> 6;
  const int m0 = blockIdx.y * 128, n0 = blockIdx.x * 128;
  const int wr = wid >> 1, wc = wid & 1;
  f32x4 acc[4][4] = {};
  gemm_mainloop(Ob, WoT, As, Bs, m0, n0, lane, wid, wr, wc, acc);
#pragma unroll
  for (int mi = 0; mi < 4; ++mi) {
    const int mrow = m0 + wr * 64 + mi * 16 + ((lane >> 4) << 2);
#pragma unroll
    for (int ni = 0; ni < 4; ++ni) {
      const int n = n0 + wc * 64 + ni * 16 + (lane & 15);
#pragma unroll
      for (int r = 0; r < 4; ++r)
        out[(size_t)(mrow + r) * 1024 + n] = acc[mi][ni][r];
    }
  }
}

// ------------------------------------------------------------------
extern "C" void kernel_launch(void* const* d_in, const int* in_sizes, int n_in,
                              void* d_out, int out_size, void* d_ws, size_t ws_size,
                              hipStream_t stream) {
  const float* x     = (const float*)d_in[0];
  const float* w_qkv = (const float*)d_in[1];
  const float* w_o   = (const float*)d_in[2];
  float* out = (float*)d_out;
  char* ws = (char*)d_ws;

  const size_t MB = 1 << 20;
  float* ct = (float*)(ws);                          // 256 KB
  float* st = (float*)(ws + (256 << 10));            // 256 KB
  unsigned short* Xb  = (unsigned short*)(ws + (512 << 10));            // 8 MB  (reused as Ob)
  unsigned short* WqT = (unsigned short*)(ws + (512 << 10) + 8  * MB);  // 6 MB
  unsigned short* WoT = (unsigned short*)(ws + (512 << 10) + 14 * MB);  // 2 MB
  unsigned short* Qb  = (unsigned short*)(ws + (512 << 10) + 16 * MB);  // 8 MB
  unsigned short* Kb  = (unsigned short*)(ws + (512 << 10) + 24 * MB);  // 8 MB
  unsigned short* VTb = (unsigned short*)(ws + (512 << 10) + 32 * MB);  // 8 MB
  unsigned short* Ob  = Xb;  // Xb dead after gemm1; total ws = 40.5 MB

  rope_table_kernel<<<dim3(256), dim3(256), 0, stream>>>(ct, st);
  cvt_x_kernel<<<dim3(4096), dim3(256), 0, stream>>>(x, Xb);
  transpose_kernel<<<dim3(96, 32), dim3(32, 8), 0, stream>>>(w_qkv, WqT, 1024, 3072);
  transpose_kernel<<<dim3(32, 32), dim3(32, 8), 0, stream>>>(w_o, WoT, 1024, 1024);
  gemm_qkv_kernel<<<dim3(24, 32), dim3(256), 0, stream>>>(Xb, WqT, ct, st, Qb, Kb, VTb);
  attn_kernel<<<dim3(32, 8), dim3(512), 0, stream>>>(Qb, Kb, VTb, Ob);
  gemm_out_kernel<<<dim3(8, 32), dim3(256), 0, stream>>>(Ob, WoT, out);
}

// Round 6
// 130.872 us; speedup vs baseline: 2.1215x; 1.1857x over previous
//
#include <hip/hip_runtime.h>

typedef short bf16x8 __attribute__((ext_vector_type(8)));
typedef short bf16x4 __attribute__((ext_vector_type(4)));
typedef float f32x4 __attribute__((ext_vector_type(4)));
typedef float f32x16 __attribute__((ext_vector_type(16)));
typedef int i32x4 __attribute__((ext_vector_type(4)));

#define DEVI static __device__ __forceinline__

// f32 -> bf16 round-to-nearest-even
DEVI unsigned short f2b(float f) {
  unsigned u = __float_as_uint(f);
  u += 0x7FFFu + ((u >> 16) & 1u);
  return (unsigned short)(u >> 16);
}

DEVI void gload16(const void* g, void* l) {
  __builtin_amdgcn_global_load_lds((const __attribute__((address_space(1))) void*)g,
                                   (__attribute__((address_space(3))) void*)l, 16, 0, 0);
}

// permlane32_swap: outa = {a.row0, b.row0}, outb = {a.row1, b.row1}
DEVI void pl32swap(int a, int b, int& outa, int& outb) {
#if __has_builtin(__builtin_amdgcn_permlane32_swap)
  auto r = __builtin_amdgcn_permlane32_swap(a, b, false, false);
  outa = ((const int*)&r)[0];
  outb = ((const int*)&r)[1];
#else
  int bp = __shfl_xor(b, 32);
  int ap = __shfl_xor(a, 32);
  outa = (threadIdx.x & 32) ? bp : a;
  outb = (threadIdx.x & 32) ? b : ap;
#endif
}

DEVI float halfmax(float x) {
  int o0, o1;
  pl32swap(__float_as_int(x), __float_as_int(x), o0, o1);
  return fmaxf(__int_as_float(o0), __int_as_float(o1));
}
DEVI float halfsum(float x) {
  int o0, o1;
  pl32swap(__float_as_int(x), __float_as_int(x), o0, o1);
  return __int_as_float(o0) + __int_as_float(o1);
}

// ------------------------------------------------------------------
// RoPE tables: ct/st[s][j], s<2048, j<32 (f32)
// ------------------------------------------------------------------
__global__ void rope_table_kernel(float* __restrict__ ct, float* __restrict__ st) {
  int i = blockIdx.x * 256 + threadIdx.x;     // 65536 total
  int s = i >> 5, j = i & 31;
  float inv = powf(10000.0f, -(float)j * (1.0f / 32.0f));
  float a = (float)s * inv;
  ct[i] = cosf(a);
  st[i] = sinf(a);
}

// ------------------------------------------------------------------
// x f32 -> bf16 (vectorized)
// ------------------------------------------------------------------
__global__ void cvt_x_kernel(const float* __restrict__ x, unsigned short* __restrict__ xb) {
  int i = blockIdx.x * 256 + threadIdx.x;     // n/4 threads
  float4 v = ((const float4*)x)[i];
  ushort4 o;
  o.x = f2b(v.x); o.y = f2b(v.y); o.z = f2b(v.z); o.w = f2b(v.w);
  ((ushort4*)xb)[i] = o;
}

// ------------------------------------------------------------------
// W [K][N] f32  ->  WT [N][K] bf16  (LDS 32x32 tile transpose)
// ------------------------------------------------------------------
__global__ void transpose_kernel(const float* __restrict__ W, unsigned short* __restrict__ WT,
                                 int K, int N) {
  __shared__ float tile[32][33];
  int n0 = blockIdx.x * 32, k0 = blockIdx.y * 32;
  int tx = threadIdx.x, ty = threadIdx.y;     // 32 x 8
#pragma unroll
  for (int i = 0; i < 32; i += 8)
    tile[ty + i][tx] = W[(size_t)(k0 + ty + i) * N + n0 + tx];
  __syncthreads();
#pragma unroll
  for (int i = 0; i < 32; i += 8)
    WT[(size_t)(n0 + ty + i) * K + k0 + tx] = f2b(tile[tx][ty + i]);
}

// ------------------------------------------------------------------
// Shared GEMM main loop v2: C[128x128] tile, A [M][1024] bf16, B^T [N][1024] bf16
// 4 waves (2x2), 4x4 frags of 16x16x32 MFMA, BK=64, K=1024 (16 tiles).
// Double-buffered LDS (stage issued BEFORE compute, 1 barrier/iter) +
// both-sides XOR chunk swizzle (pre-swizzled global src, XOR'd ds_read).
// ------------------------------------------------------------------
DEVI void gemm_mainloop(const unsigned short* __restrict__ A, const unsigned short* __restrict__ B,
                        unsigned short* As, unsigned short* Bs,   // each [2][128*64]
                        int m0, int n0, int lane, int wid, int wr, int wc,
                        f32x4 acc[4][4]) {
  const int srow = lane >> 3;
  const int scc = ((lane & 7) ^ srow) * 8;    // swizzled source col (elements)
  auto stage = [&](int k0, int nb) {
    unsigned short* Ad = As + nb * 8192;
    unsigned short* Bd = Bs + nb * 8192;
#pragma unroll
    for (int i = 0; i < 4; ++i) {
      const int c = i * 4 + wid;
      const int row = c * 8 + srow;
      gload16(A + (size_t)(m0 + row) * 1024 + k0 + scc, (char*)Ad + c * 1024);
      gload16(B + (size_t)(n0 + row) * 1024 + k0 + scc, (char*)Bd + c * 1024);
    }
  };
  stage(0, 0);
  __syncthreads();
  const int rx = lane & 7;
  for (int t = 0; t < 16; ++t) {
    const int cur = t & 1;
    if (t < 15) stage((t + 1) * 64, cur ^ 1);
    const unsigned short* Ab = As + cur * 8192;
    const unsigned short* Bb = Bs + cur * 8192;
#pragma unroll
    for (int kk = 0; kk < 64; kk += 32) {
      const int cc = (((kk >> 3) + (lane >> 4)) ^ rx) * 8;
      bf16x8 a[4], b[4];
#pragma unroll
      for (int mi = 0; mi < 4; ++mi)
        a[mi] = *(const bf16x8*)&Ab[(wr * 64 + mi * 16 + (lane & 15)) * 64 + cc];
#pragma unroll
      for (int ni = 0; ni < 4; ++ni)
        b[ni] = *(const bf16x8*)&Bb[(wc * 64 + ni * 16 + (lane & 15)) * 64 + cc];
#pragma unroll
      for (int mi = 0; mi < 4; ++mi)
#pragma unroll
        for (int ni = 0; ni < 4; ++ni)
          acc[mi][ni] = __builtin_amdgcn_mfma_f32_16x16x32_bf16(a[mi], b[ni], acc[mi][ni], 0, 0, 0);
    }
    __syncthreads();
  }
}

// ------------------------------------------------------------------
// GEMM1: qkv = Xb @ WqT^T with fused RoPE; scatter Q[B,H,S,64] K[B,H,S,64] VT[B,H,64,S]
// grid (24, 32)
// ------------------------------------------------------------------
__global__ __launch_bounds__(256) void gemm_qkv_kernel(
    const unsigned short* __restrict__ Xb, const unsigned short* __restrict__ WT,
    const float* __restrict__ ct, const float* __restrict__ st,
    unsigned short* __restrict__ Qb, unsigned short* __restrict__ Kb,
    unsigned short* __restrict__ VTb) {
  __shared__ unsigned short As[2][128 * 64];
  __shared__ unsigned short Bs[2][128 * 64];
  const int lane = threadIdx.x & 63, wid = threadIdx.x >> 6;
  const int m0 = blockIdx.y * 128, n0 = blockIdx.x * 128;
  const int wr = wid >> 1, wc = wid & 1;
  f32x4 acc[4][4] = {};
  gemm_mainloop(Xb, WT, &As[0][0], &Bs[0][0], m0, n0, lane, wid, wr, wc, acc);

  // wave covers exactly one head: n in [n_base, n_base+64)
  const int n_base = n0 + wc * 64;
  const int t = n_base >> 10;                 // 0=q 1=k 2=v
  const int h = (n_base & 1023) >> 6;
  if (t < 2) {
    unsigned short* dst = (t == 0) ? Qb : Kb;
#pragma unroll
    for (int mi = 0; mi < 4; ++mi) {
      const int mrow = m0 + wr * 64 + mi * 16 + ((lane >> 4) << 2);
#pragma unroll
      for (int r = 0; r < 4; ++r) {
        const int m = mrow + r;
        const int s = m & 2047, bb = m >> 11;
        const size_t base = ((size_t)(bb * 16 + h) * 2048 + s) * 64;
#pragma unroll
        for (int ni = 0; ni < 2; ++ni) {
          const int j = ni * 16 + (lane & 15);
          const float c = ct[s * 32 + j], sn = st[s * 32 + j];
          const float x1 = acc[mi][ni][r], x2 = acc[mi][ni + 2][r];
          dst[base + j]      = f2b(x1 * c + x2 * sn);
          dst[base + j + 32] = f2b(-x1 * sn + x2 * c);
        }
      }
    }
  } else {
#pragma unroll
    for (int mi = 0; mi < 4; ++mi) {
      const int mrow = m0 + wr * 64 + mi * 16 + ((lane >> 4) << 2);
      const int s = mrow & 2047, bb = mrow >> 11;
#pragma unroll
      for (int ni = 0; ni < 4; ++ni) {
        const int d = ni * 16 + (lane & 15);
        ushort4 o;
        o.x = f2b(acc[mi][ni][0]); o.y = f2b(acc[mi][ni][1]);
        o.z = f2b(acc[mi][ni][2]); o.w = f2b(acc[mi][ni][3]);
        *(ushort4*)&VTb[((size_t)(bb * 16 + h) * 64 + d) * 2048 + s] = o;
      }
    }
  }
}

// ------------------------------------------------------------------
// Flash attention v6 (causal). grid (32 bh, 8 p), 512 threads (8 waves).
// KEY-SPLIT UNIFORM WAVES: wave (s=wid&3, half=wid>>2) owns q-strip s of BOTH
// q-tiles jA=15-p and jB=p, and processes only 64-key tiles with parity==half
// -> every wave ~34 subtiles, 2 ACTIVE waves/SIMD all kernel, 17 iterations.
// Partial (m,l,acc) merged between halves via LDS at the end (flash split-K).
// 128-key staging per iteration (double-buffered, XOR swizzle both-sides).
// ------------------------------------------------------------------
DEVI void stage128(const unsigned short* __restrict__ Kh, const unsigned short* __restrict__ Vh,
                   int kbase, unsigned char* buf /* 32 KB: [half][K 8K | V 8K] */, int tid) {
  const int r = tid >> 3, c = tid & 7, cc = c ^ (r & 7);
  const int dst = (tid & ~63) * 16;
#pragma unroll
  for (int q = 0; q < 2; ++q) {
    unsigned char* b = buf + q * 16384;
    gload16(Kh + (size_t)(kbase + q * 64 + r) * 64 + cc * 8, b + dst);
    gload16(Vh + (size_t)r * 2048 + kbase + q * 64 + cc * 8, b + 8192 + dst);
  }
}

DEVI void attn_sub(const unsigned char* __restrict__ bufK, const unsigned char* __restrict__ bufV,
                   const bf16x8 qf[4], int s32, int kglob, bool diag, int qg, int ln, int hi,
                   float& m2, float& l_run, f32x16& acc0, f32x16& acc1) {
  const float C = 0.125f * 1.44269504f;       // scale * log2(e)
  const int rx = ln & 7;
  bf16x8 kf[4];
#pragma unroll
  for (int j = 0; j < 4; ++j) {
    const int cc = (2 * j + hi) ^ rx;
    kf[j] = *(const bf16x8*)(bufK + (s32 * 32 + ln) * 128 + cc * 16);
  }
  bf16x8 v0[2], v1[2];
#pragma unroll
  for (int p = 0; p < 2; ++p) {
    const int cc = (4 * s32 + 2 * p + hi) ^ rx;
    v0[p] = *(const bf16x8*)(bufV + ln * 128 + cc * 16);
    v1[p] = *(const bf16x8*)(bufV + (ln + 32) * 128 + cc * 16);
  }

  f32x16 stv = {};
  __builtin_amdgcn_s_setprio(1);
  stv = __builtin_amdgcn_mfma_f32_32x32x16_bf16(kf[0], qf[0], stv, 0, 0, 0);
  stv = __builtin_amdgcn_mfma_f32_32x32x16_bf16(kf[1], qf[1], stv, 0, 0, 0);
  stv = __builtin_amdgcn_mfma_f32_32x32x16_bf16(kf[2], qf[2], stv, 0, 0, 0);
  stv = __builtin_amdgcn_mfma_f32_32x32x16_bf16(kf[3], qf[3], stv, 0, 0, 0);
  __builtin_amdgcn_s_setprio(0);

  // lane holds S^T[key = kglob+(r&3)+8*(r>>2)+4*hi][q], raw domain
  float sraw[16];
#pragma unroll
  for (int r = 0; r < 16; ++r) sraw[r] = stv[r];
  if (diag) {
#pragma unroll
    for (int r = 0; r < 16; ++r) {
      const int kg = kglob + (r & 3) + ((r >> 2) << 3) + (hi << 2);
      if (kg > qg) sraw[r] = -1e30f;
    }
  }
  float mraw = sraw[0];
#pragma unroll
  for (int r = 1; r < 16; ++r) mraw = fmaxf(mraw, sraw[r]);
  const float mloc = halfmax(mraw * C);       // scaled log2 domain
  // defer-max: only rescale acc when max grew by >8 nats (11.54 in log2)
  if (__any(mloc > m2 + 11.5416f)) {
    const float mnew = fmaxf(m2, mloc);
    const float sc = exp2f(m2 - mnew);
    l_run *= sc;
#pragma unroll
    for (int r = 0; r < 16; ++r) { acc0[r] *= sc; acc1[r] *= sc; }
    m2 = mnew;
  }
  float p[16], ps = 0.f;
#pragma unroll
  for (int r = 0; r < 16; ++r) { p[r] = exp2f(fmaf(sraw[r], C, -m2)); ps += p[r]; }
  l_run += halfsum(ps);

  // P^T -> bf16 fragments (B-operand: n=q, k=key_local=hi*8+j)
  int cw[8];
#pragma unroll
  for (int i = 0; i < 8; ++i)
    asm("v_cvt_pk_bf16_f32 %0, %1, %2" : "=v"(cw[i]) : "v"(p[2 * i]), "v"(p[2 * i + 1]));
  int a0, a1, b0, b1, a2, a3, b2, b3;
  pl32swap(cw[0], cw[2], a0, b0);   // keys kglob+0..15
  pl32swap(cw[1], cw[3], a1, b1);
  pl32swap(cw[4], cw[6], a2, b2);   // keys kglob+16..31
  pl32swap(cw[5], cw[7], a3, b3);
  const bf16x8 pa0 = __builtin_bit_cast(bf16x8, (i32x4){a0, a1, b0, b1});
  const bf16x8 pa1 = __builtin_bit_cast(bf16x8, (i32x4){a2, a3, b2, b3});

  __builtin_amdgcn_s_setprio(1);
  acc0 = __builtin_amdgcn_mfma_f32_32x32x16_bf16(v0[0], pa0, acc0, 0, 0, 0);
  acc0 = __builtin_amdgcn_mfma_f32_32x32x16_bf16(v0[1], pa1, acc0, 0, 0, 0);
  acc1 = __builtin_amdgcn_mfma_f32_32x32x16_bf16(v1[0], pa0, acc1, 0, 0, 0);
  acc1 = __builtin_amdgcn_mfma_f32_32x32x16_bf16(v1[1], pa1, acc1, 0, 0, 0);
  __builtin_amdgcn_s_setprio(0);
}

DEVI void write_partial(float* M, int slot, const f32x16& a0, const f32x16& a1,
                        float m2, float l) {
#pragma unroll
  for (int r = 0; r < 16; ++r) { M[slot + r] = a0[r]; M[slot + 16 + r] = a1[r]; }
  M[slot + 32] = m2;
  M[slot + 33] = l;
}

DEVI void write_merged(unsigned short* __restrict__ Ob, const float* M, int slot,
                       const f32x16& acc0, const f32x16& acc1, float m2, float l_run,
                       int bh, int q0, int ln, int hi) {
  const float mp = M[slot + 32], lp = M[slot + 33];
  const float m = fmaxf(m2, mp);
  const float eo = exp2f(m2 - m), ep = exp2f(mp - m);
  const float il = 1.0f / (l_run * eo + lp * ep);
  const int b = bh >> 4, h = bh & 15;
  unsigned short* ob = Ob + ((size_t)(b * 2048 + q0 + ln)) * 1024 + h * 64;
#pragma unroll
  for (int g = 0; g < 4; ++g) {
    ushort4 o0, o1;
    o0.x = f2b((acc0[4 * g + 0] * eo + M[slot + 4 * g + 0] * ep) * il);
    o0.y = f2b((acc0[4 * g + 1] * eo + M[slot + 4 * g + 1] * ep) * il);
    o0.z = f2b((acc0[4 * g + 2] * eo + M[slot + 4 * g + 2] * ep) * il);
    o0.w = f2b((acc0[4 * g + 3] * eo + M[slot + 4 * g + 3] * ep) * il);
    o1.x = f2b((acc1[4 * g + 0] * eo + M[slot + 16 + 4 * g + 0] * ep) * il);
    o1.y = f2b((acc1[4 * g + 1] * eo + M[slot + 16 + 4 * g + 1] * ep) * il);
    o1.z = f2b((acc1[4 * g + 2] * eo + M[slot + 16 + 4 * g + 2] * ep) * il);
    o1.w = f2b((acc1[4 * g + 3] * eo + M[slot + 16 + 4 * g + 3] * ep) * il);
    *(ushort4*)&ob[8 * g + 4 * hi]      = o0;   // dt=0
    *(ushort4*)&ob[32 + 8 * g + 4 * hi] = o1;   // dt=1
  }
}

__global__ __launch_bounds__(512) void attn_kernel(
    const unsigned short* __restrict__ Qb, const unsigned short* __restrict__ Kb,
    const unsigned short* __restrict__ VTb, unsigned short* __restrict__ Ob) {
  __shared__ unsigned char smem[2][2][16384];   // [dbuf][half][K 8K | V 8K]
  const int tid = threadIdx.x;
  const int lane = tid & 63, wid = tid >> 6;
  const int ln = lane & 31, hi = lane >> 5;
  const int s = wid & 3, half = wid >> 2;
  const int bh = blockIdx.x;
  const int p = blockIdx.y;
  const int jA = 15 - p, jB = p;
  const unsigned short* Qh = Qb + (size_t)bh * 2048 * 64;
  const unsigned short* Kh = Kb + (size_t)bh * 2048 * 64;
  const unsigned short* Vh = VTb + (size_t)bh * 64 * 2048;

  f32x16 aA0 = {}, aA1 = {}, aB0 = {}, aB1 = {};
  float mA = -1e30f, lA = 0.f, mB = -1e30f, lB = 0.f;
  int it = 0;

  auto load_q = [&](int q0, bf16x8 qf[4]) {
    const unsigned short* pq = Qh + (size_t)(q0 + ln) * 64 + hi * 8;
#pragma unroll
    for (int t = 0; t < 4; ++t) qf[t] = *(const bf16x8*)(pq + t * 16);
  };
  auto run_phase = [&](int j, const bf16x8 qf[4], f32x16& acc0, f32x16& acc1,
                       float& m2, float& l_run, int q0, int nextFirst) {
    const int qg = q0 + ln;
    const int top = q0 >> 5;
    for (int kb = 0; kb <= j; ++kb, ++it) {
      const int nxt = (kb < j) ? (kb + 1) * 128 : nextFirst;
      if (nxt >= 0) stage128(Kh, Vh, nxt, &smem[(it + 1) & 1][0][0], tid);
      const unsigned char* bufK = &smem[it & 1][half][0];
      const unsigned char* bufV = bufK + 8192;
      const int t64 = 2 * kb + half;
#pragma unroll
      for (int s32 = 0; s32 < 2; ++s32) {
        const int g32 = 2 * t64 + s32;
        if (g32 <= top)
          attn_sub(bufK, bufV, qf, s32, g32 * 32, g32 == top, qg, ln, hi, m2, l_run, acc0, acc1);
      }
      __syncthreads();
    }
  };

  bf16x8 qfA[4];
  load_q(jA * 128 + s * 32, qfA);
  stage128(Kh, Vh, 0, &smem[0][0][0], tid);
  __syncthreads();
  run_phase(jA, qfA, aA0, aA1, mA, lA, jA * 128 + s * 32, /*nextFirst=*/0);
  bf16x8 qfB[4];
  load_q(jB * 128 + s * 32, qfB);
  run_phase(jB, qfB, aB0, aB1, mB, lB, jB * 128 + s * 32, /*nextFirst=*/-1);

  // ---- split-K merge between halves (flash combine), then final O writes ----
  float* M = (float*)&smem[0][0][0];          // 34 KB used of 64 KB
  const int slot = (s * 64 + lane) * 34;
  if (half == 1) write_partial(M, slot, aA0, aA1, mA, lA);
  __syncthreads();
  if (half == 0) write_merged(Ob, M, slot, aA0, aA1, mA, lA, bh, jA * 128 + s * 32, ln, hi);
  __syncthreads();
  if (half == 0) write_partial(M, slot, aB0, aB1, mB, lB);
  __syncthreads();
  if (half == 1) write_merged(Ob, M, slot, aB0, aB1, mB, lB, bh, jB * 128 + s * 32, ln, hi);
}

// ------------------------------------------------------------------
// GEMM2: out = Ob @ WoT^T, f32 epilogue. grid (8, 32)
// ------------------------------------------------------------------
__global__ __launch_bounds__(256) void gemm_out_kernel(
    const unsigned short* __restrict__ Ob, const unsigned short* __restrict__ WoT,
    float* __restrict__ out) {
  __shared__ unsigned short As[2][128 * 64];
  __shared__ unsigned short Bs[2][128 * 64];
  const int lane = threadIdx.x & 63, wid = threadIdx.x >> 6;
  const int m0 = blockIdx.y * 128, n0 = blockIdx.x * 128;
  const int wr = wid >> 1, wc = wid & 1;
  f32x4 acc[4][4] = {};
  gemm_mainloop(Ob, WoT, &As[0][0], &Bs[0][0], m0, n0, lane, wid, wr, wc, acc);
#pragma unroll
  for (int mi = 0; mi < 4; ++mi) {
    const int mrow = m0 + wr * 64 + mi * 16 + ((lane >> 4) << 2);
#pragma unroll
    for (int ni = 0; ni < 4; ++ni) {
      const int n = n0 + wc * 64 + ni * 16 + (lane & 15);
#pragma unroll
      for (int r = 0; r < 4; ++r)
        out[(size_t)(mrow + r) * 1024 + n] = acc[mi][ni][r];
    }
  }
}

// ------------------------------------------------------------------
extern "C" void kernel_launch(void* const* d_in, const int* in_sizes, int n_in,
                              void* d_out, int out_size, void* d_ws, size_t ws_size,
                              hipStream_t stream) {
  const float* x     = (const float*)d_in[0];
  const float* w_qkv = (const float*)d_in[1];
  const float* w_o   = (const float*)d_in[2];
  float* out = (float*)d_out;
  char* ws = (char*)d_ws;

  const size_t MB = 1 << 20;
  float* ct = (float*)(ws);                          // 256 KB
  float* st = (float*)(ws + (256 << 10));            // 256 KB
  unsigned short* Xb  = (unsigned short*)(ws + (512 << 10));            // 8 MB  (reused as Ob)
  unsigned short* WqT = (unsigned short*)(ws + (512 << 10) + 8  * MB);  // 6 MB
  unsigned short* WoT = (unsigned short*)(ws + (512 << 10) + 14 * MB);  // 2 MB
  unsigned short* Qb  = (unsigned short*)(ws + (512 << 10) + 16 * MB);  // 8 MB
  unsigned short* Kb  = (unsigned short*)(ws + (512 << 10) + 24 * MB);  // 8 MB
  unsigned short* VTb = (unsigned short*)(ws + (512 << 10) + 32 * MB);  // 8 MB
  unsigned short* Ob  = Xb;  // Xb dead after gemm1; total ws = 40.5 MB

  rope_table_kernel<<<dim3(256), dim3(256), 0, stream>>>(ct, st);
  cvt_x_kernel<<<dim3(4096), dim3(256), 0, stream>>>(x, Xb);
  transpose_kernel<<<dim3(96, 32), dim3(32, 8), 0, stream>>>(w_qkv, WqT, 1024, 3072);
  transpose_kernel<<<dim3(32, 32), dim3(32, 8), 0, stream>>>(w_o, WoT, 1024, 1024);
  gemm_qkv_kernel<<<dim3(24, 32), dim3(256), 0, stream>>>(Xb, WqT, ct, st, Qb, Kb, VTb);
  attn_kernel<<<dim3(32, 8), dim3(512), 0, stream>>>(Qb, Kb, VTb, Ob);
  gemm_out_kernel<<<dim3(8, 32), dim3(256), 0, stream>>>(Ob, WoT, out);
}

// Round 7
// 123.494 us; speedup vs baseline: 2.2483x; 1.0597x over previous
//
#include <hip/hip_runtime.h>

typedef short bf16x8 __attribute__((ext_vector_type(8)));
typedef short bf16x4 __attribute__((ext_vector_type(4)));
typedef float f32x4 __attribute__((ext_vector_type(4)));
typedef float f32x16 __attribute__((ext_vector_type(16)));
typedef int i32x4 __attribute__((ext_vector_type(4)));

#define DEVI static __device__ __forceinline__

// f32 -> bf16 round-to-nearest-even
DEVI unsigned short f2b(float f) {
  unsigned u = __float_as_uint(f);
  u += 0x7FFFu + ((u >> 16) & 1u);
  return (unsigned short)(u >> 16);
}

DEVI void gload16(const void* g, void* l) {
  __builtin_amdgcn_global_load_lds((const __attribute__((address_space(1))) void*)g,
                                   (__attribute__((address_space(3))) void*)l, 16, 0, 0);
}

// permlane32_swap: outa = {a.row0, b.row0}, outb = {a.row1, b.row1}
DEVI void pl32swap(int a, int b, int& outa, int& outb) {
#if __has_builtin(__builtin_amdgcn_permlane32_swap)
  auto r = __builtin_amdgcn_permlane32_swap(a, b, false, false);
  outa = ((const int*)&r)[0];
  outb = ((const int*)&r)[1];
#else
  int bp = __shfl_xor(b, 32);
  int ap = __shfl_xor(a, 32);
  outa = (threadIdx.x & 32) ? bp : a;
  outb = (threadIdx.x & 32) ? b : ap;
#endif
}

DEVI float halfmax(float x) {
  int o0, o1;
  pl32swap(__float_as_int(x), __float_as_int(x), o0, o1);
  return fmaxf(__int_as_float(o0), __int_as_float(o1));
}
DEVI float halfsum(float x) {
  int o0, o1;
  pl32swap(__float_as_int(x), __float_as_int(x), o0, o1);
  return __int_as_float(o0) + __int_as_float(o1);
}

// ------------------------------------------------------------------
// RoPE tables: ct/st[s][j], s<2048, j<32 (f32)
// ------------------------------------------------------------------
__global__ void rope_table_kernel(float* __restrict__ ct, float* __restrict__ st) {
  int i = blockIdx.x * 256 + threadIdx.x;     // 65536 total
  int s = i >> 5, j = i & 31;
  float inv = powf(10000.0f, -(float)j * (1.0f / 32.0f));
  float a = (float)s * inv;
  ct[i] = cosf(a);
  st[i] = sinf(a);
}

// ------------------------------------------------------------------
// x f32 -> bf16 (vectorized)
// ------------------------------------------------------------------
__global__ void cvt_x_kernel(const float* __restrict__ x, unsigned short* __restrict__ xb) {
  int i = blockIdx.x * 256 + threadIdx.x;     // n/4 threads
  float4 v = ((const float4*)x)[i];
  ushort4 o;
  o.x = f2b(v.x); o.y = f2b(v.y); o.z = f2b(v.z); o.w = f2b(v.w);
  ((ushort4*)xb)[i] = o;
}

// ------------------------------------------------------------------
// W [K][N] f32  ->  WT [N][K] bf16  (LDS 32x32 tile transpose)
// ------------------------------------------------------------------
__global__ void transpose_kernel(const float* __restrict__ W, unsigned short* __restrict__ WT,
                                 int K, int N) {
  __shared__ float tile[32][33];
  int n0 = blockIdx.x * 32, k0 = blockIdx.y * 32;
  int tx = threadIdx.x, ty = threadIdx.y;     // 32 x 8
#pragma unroll
  for (int i = 0; i < 32; i += 8)
    tile[ty + i][tx] = W[(size_t)(k0 + ty + i) * N + n0 + tx];
  __syncthreads();
#pragma unroll
  for (int i = 0; i < 32; i += 8)
    WT[(size_t)(n0 + ty + i) * K + k0 + tx] = f2b(tile[tx][ty + i]);
}

// ------------------------------------------------------------------
// GEMM1 v3: 256x256 tile, BK=64, 8 waves (2x4), rolling counted-vmcnt
// pipeline (T3+T4): stage t+2 issued after compute-t barrier; vmcnt(8)
// keeps next tile's loads in flight ACROSS the barrier (never drain to 0
// in the loop). Chunk-XOR swizzle both-sides (verified, conflicts=0).
// Fused RoPE epilogue; scatter Q[B,H,S,64] K[B,H,S,64] VT[B,H,64,S].
// grid (12, 16), 512 threads, LDS 128KB (1 block/CU).
// ------------------------------------------------------------------
__global__ __launch_bounds__(512, 2) void gemm_qkv_kernel(
    const unsigned short* __restrict__ Xb, const unsigned short* __restrict__ WT,
    const float* __restrict__ ct, const float* __restrict__ st,
    unsigned short* __restrict__ Qb, unsigned short* __restrict__ Kb,
    unsigned short* __restrict__ VTb) {
  __shared__ unsigned short As[2][256 * 64];   // 64 KB
  __shared__ unsigned short Bs[2][256 * 64];   // 64 KB
  const int tid = threadIdx.x;
  const int lane = tid & 63, wid = tid >> 6;
  const int m0 = blockIdx.y * 256, n0 = blockIdx.x * 256;
  const int wr = wid >> 2, wc = wid & 3;       // wave -> 128x64 output
  const int srow = lane >> 3;
  const int scc = ((lane & 7) ^ srow) * 8;     // swizzled source col
  const int rx = lane & 7;

  f32x4 acc[8][4] = {};

  auto stage = [&](int k0, int nb) {           // 8 gload_lds / thread
    unsigned short* Ad = As[nb];
    unsigned short* Bd = Bs[nb];
#pragma unroll
    for (int i = 0; i < 4; ++i) {
      const int c = i * 8 + wid;               // 0..31
      const int row = c * 8 + srow;            // 0..255
      gload16(Xb + (size_t)(m0 + row) * 1024 + k0 + scc, (char*)Ad + c * 1024);
      gload16(WT + (size_t)(n0 + row) * 1024 + k0 + scc, (char*)Bd + c * 1024);
    }
  };
  auto compute = [&](int nb) {                 // 64 MFMA / wave
    const unsigned short* Ab = As[nb];
    const unsigned short* Bb = Bs[nb];
#pragma unroll
    for (int kk = 0; kk < 64; kk += 32) {
      const int cc = (((kk >> 3) + (lane >> 4)) ^ rx) * 8;
      bf16x8 a[8], b[4];
#pragma unroll
      for (int mi = 0; mi < 8; ++mi)
        a[mi] = *(const bf16x8*)&Ab[(wr * 128 + mi * 16 + (lane & 15)) * 64 + cc];
#pragma unroll
      for (int ni = 0; ni < 4; ++ni)
        b[ni] = *(const bf16x8*)&Bb[(wc * 64 + ni * 16 + (lane & 15)) * 64 + cc];
      __builtin_amdgcn_s_setprio(1);
#pragma unroll
      for (int mi = 0; mi < 8; ++mi)
#pragma unroll
        for (int ni = 0; ni < 4; ++ni)
          acc[mi][ni] = __builtin_amdgcn_mfma_f32_16x16x32_bf16(a[mi], b[ni], acc[mi][ni], 0, 0, 0);
      __builtin_amdgcn_s_setprio(0);
    }
  };

  stage(0, 0);
  stage(64, 1);
  for (int t = 0; t < 15; ++t) {
    asm volatile("s_waitcnt vmcnt(8)" ::: "memory");   // tile t landed; t+1 in flight
    __builtin_amdgcn_s_barrier();
    compute(t & 1);
    __builtin_amdgcn_s_barrier();                      // all waves done reading buf
    if (t < 14) stage((t + 2) * 64, t & 1);            // refill freed buffer
  }
  asm volatile("s_waitcnt vmcnt(0)" ::: "memory");
  __builtin_amdgcn_s_barrier();
  compute(1);

  // ---- fused RoPE epilogue; wave covers one head chunk (64 cols) ----
  const int n_base = n0 + wc * 64;
  const int ty = n_base >> 10;                 // 0=q 1=k 2=v
  const int h = (n_base & 1023) >> 6;
  if (ty < 2) {
    unsigned short* dst = (ty == 0) ? Qb : Kb;
#pragma unroll
    for (int mi = 0; mi < 8; ++mi) {
      const int mrow = m0 + wr * 128 + mi * 16 + ((lane >> 4) << 2);
#pragma unroll
      for (int r = 0; r < 4; ++r) {
        const int m = mrow + r;
        const int s = m & 2047, bb = m >> 11;
        const size_t base = ((size_t)(bb * 16 + h) * 2048 + s) * 64;
#pragma unroll
        for (int ni = 0; ni < 2; ++ni) {
          const int j = ni * 16 + (lane & 15);
          const float c = ct[s * 32 + j], sn = st[s * 32 + j];
          const float x1 = acc[mi][ni][r], x2 = acc[mi][ni + 2][r];
          dst[base + j]      = f2b(x1 * c + x2 * sn);
          dst[base + j + 32] = f2b(-x1 * sn + x2 * c);
        }
      }
    }
  } else {
#pragma unroll
    for (int mi = 0; mi < 8; ++mi) {
      const int mrow = m0 + wr * 128 + mi * 16 + ((lane >> 4) << 2);
      const int s = mrow & 2047, bb = mrow >> 11;
#pragma unroll
      for (int ni = 0; ni < 4; ++ni) {
        const int d = ni * 16 + (lane & 15);
        ushort4 o;
        o.x = f2b(acc[mi][ni][0]); o.y = f2b(acc[mi][ni][1]);
        o.z = f2b(acc[mi][ni][2]); o.w = f2b(acc[mi][ni][3]);
        *(ushort4*)&VTb[((size_t)(bb * 16 + h) * 64 + d) * 2048 + s] = o;
      }
    }
  }
}

// ------------------------------------------------------------------
// GEMM2 mainloop: 128x128 tile, 4 waves, same rolling counted-vmcnt
// pipeline. LDS 64 KB -> 2 blocks/CU resident (grid 256 = 1/CU).
// ------------------------------------------------------------------
DEVI void gemm_mainloop(const unsigned short* __restrict__ A, const unsigned short* __restrict__ B,
                        unsigned short* As, unsigned short* Bs,   // each [2][8192]
                        int m0, int n0, int lane, int wid, int wr, int wc,
                        f32x4 acc[4][4]) {
  const int srow = lane >> 3;
  const int scc = ((lane & 7) ^ srow) * 8;
  const int rx = lane & 7;
  auto stage = [&](int k0, int nb) {           // 8 gload_lds / thread
    unsigned short* Ad = As + nb * 8192;
    unsigned short* Bd = Bs + nb * 8192;
#pragma unroll
    for (int i = 0; i < 4; ++i) {
      const int c = i * 4 + wid;
      const int row = c * 8 + srow;
      gload16(A + (size_t)(m0 + row) * 1024 + k0 + scc, (char*)Ad + c * 1024);
      gload16(B + (size_t)(n0 + row) * 1024 + k0 + scc, (char*)Bd + c * 1024);
    }
  };
  auto compute = [&](int nb) {
    const unsigned short* Ab = As + nb * 8192;
    const unsigned short* Bb = Bs + nb * 8192;
#pragma unroll
    for (int kk = 0; kk < 64; kk += 32) {
      const int cc = (((kk >> 3) + (lane >> 4)) ^ rx) * 8;
      bf16x8 a[4], b[4];
#pragma unroll
      for (int mi = 0; mi < 4; ++mi)
        a[mi] = *(const bf16x8*)&Ab[(wr * 64 + mi * 16 + (lane & 15)) * 64 + cc];
#pragma unroll
      for (int ni = 0; ni < 4; ++ni)
        b[ni] = *(const bf16x8*)&Bb[(wc * 64 + ni * 16 + (lane & 15)) * 64 + cc];
      __builtin_amdgcn_s_setprio(1);
#pragma unroll
      for (int mi = 0; mi < 4; ++mi)
#pragma unroll
        for (int ni = 0; ni < 4; ++ni)
          acc[mi][ni] = __builtin_amdgcn_mfma_f32_16x16x32_bf16(a[mi], b[ni], acc[mi][ni], 0, 0, 0);
      __builtin_amdgcn_s_setprio(0);
    }
  };
  stage(0, 0);
  stage(64, 1);
  for (int t = 0; t < 15; ++t) {
    asm volatile("s_waitcnt vmcnt(8)" ::: "memory");
    __builtin_amdgcn_s_barrier();
    compute(t & 1);
    __builtin_amdgcn_s_barrier();
    if (t < 14) stage((t + 2) * 64, t & 1);
  }
  asm volatile("s_waitcnt vmcnt(0)" ::: "memory");
  __builtin_amdgcn_s_barrier();
  compute(1);
}

// ------------------------------------------------------------------
// Flash attention v6 (causal). grid (32 bh, 8 p), 512 threads (8 waves).
// KEY-SPLIT UNIFORM WAVES: wave (s=wid&3, half=wid>>2) owns q-strip s of BOTH
// q-tiles jA=15-p and jB=p, and processes only 64-key tiles with parity==half
// -> every wave ~34 subtiles, 2 ACTIVE waves/SIMD all kernel, 17 iterations.
// Partial (m,l,acc) merged between halves via LDS at the end (flash split-K).
// 128-key staging per iteration (double-buffered, XOR swizzle both-sides).
// ------------------------------------------------------------------
DEVI void stage128(const unsigned short* __restrict__ Kh, const unsigned short* __restrict__ Vh,
                   int kbase, unsigned char* buf /* 32 KB: [half][K 8K | V 8K] */, int tid) {
  const int r = tid >> 3, c = tid & 7, cc = c ^ (r & 7);
  const int dst = (tid & ~63) * 16;
#pragma unroll
  for (int q = 0; q < 2; ++q) {
    unsigned char* b = buf + q * 16384;
    gload16(Kh + (size_t)(kbase + q * 64 + r) * 64 + cc * 8, b + dst);
    gload16(Vh + (size_t)r * 2048 + kbase + q * 64 + cc * 8, b + 8192 + dst);
  }
}

DEVI void attn_sub(const unsigned char* __restrict__ bufK, const unsigned char* __restrict__ bufV,
                   const bf16x8 qf[4], int s32, int kglob, bool diag, int qg, int ln, int hi,
                   float& m2, float& l_run, f32x16& acc0, f32x16& acc1) {
  const float C = 0.125f * 1.44269504f;       // scale * log2(e)
  const int rx = ln & 7;
  bf16x8 kf[4];
#pragma unroll
  for (int j = 0; j < 4; ++j) {
    const int cc = (2 * j + hi) ^ rx;
    kf[j] = *(const bf16x8*)(bufK + (s32 * 32 + ln) * 128 + cc * 16);
  }
  bf16x8 v0[2], v1[2];
#pragma unroll
  for (int p = 0; p < 2; ++p) {
    const int cc = (4 * s32 + 2 * p + hi) ^ rx;
    v0[p] = *(const bf16x8*)(bufV + ln * 128 + cc * 16);
    v1[p] = *(const bf16x8*)(bufV + (ln + 32) * 128 + cc * 16);
  }

  f32x16 stv = {};
  __builtin_amdgcn_s_setprio(1);
  stv = __builtin_amdgcn_mfma_f32_32x32x16_bf16(kf[0], qf[0], stv, 0, 0, 0);
  stv = __builtin_amdgcn_mfma_f32_32x32x16_bf16(kf[1], qf[1], stv, 0, 0, 0);
  stv = __builtin_amdgcn_mfma_f32_32x32x16_bf16(kf[2], qf[2], stv, 0, 0, 0);
  stv = __builtin_amdgcn_mfma_f32_32x32x16_bf16(kf[3], qf[3], stv, 0, 0, 0);
  __builtin_amdgcn_s_setprio(0);

  // lane holds S^T[key = kglob+(r&3)+8*(r>>2)+4*hi][q], raw domain
  float sraw[16];
#pragma unroll
  for (int r = 0; r < 16; ++r) sraw[r] = stv[r];
  if (diag) {
#pragma unroll
    for (int r = 0; r < 16; ++r) {
      const int kg = kglob + (r & 3) + ((r >> 2) << 3) + (hi << 2);
      if (kg > qg) sraw[r] = -1e30f;
    }
  }
  float mraw = sraw[0];
#pragma unroll
  for (int r = 1; r < 16; ++r) mraw = fmaxf(mraw, sraw[r]);
  const float mloc = halfmax(mraw * C);       // scaled log2 domain
  // defer-max: only rescale acc when max grew by >8 nats (11.54 in log2)
  if (__any(mloc > m2 + 11.5416f)) {
    const float mnew = fmaxf(m2, mloc);
    const float sc = exp2f(m2 - mnew);
    l_run *= sc;
#pragma unroll
    for (int r = 0; r < 16; ++r) { acc0[r] *= sc; acc1[r] *= sc; }
    m2 = mnew;
  }
  float p[16], ps = 0.f;
#pragma unroll
  for (int r = 0; r < 16; ++r) { p[r] = exp2f(fmaf(sraw[r], C, -m2)); ps += p[r]; }
  l_run += halfsum(ps);

  // P^T -> bf16 fragments (B-operand: n=q, k=key_local=hi*8+j)
  int cw[8];
#pragma unroll
  for (int i = 0; i < 8; ++i)
    asm("v_cvt_pk_bf16_f32 %0, %1, %2" : "=v"(cw[i]) : "v"(p[2 * i]), "v"(p[2 * i + 1]));
  int a0, a1, b0, b1, a2, a3, b2, b3;
  pl32swap(cw[0], cw[2], a0, b0);   // keys kglob+0..15
  pl32swap(cw[1], cw[3], a1, b1);
  pl32swap(cw[4], cw[6], a2, b2);   // keys kglob+16..31
  pl32swap(cw[5], cw[7], a3, b3);
  const bf16x8 pa0 = __builtin_bit_cast(bf16x8, (i32x4){a0, a1, b0, b1});
  const bf16x8 pa1 = __builtin_bit_cast(bf16x8, (i32x4){a2, a3, b2, b3});

  __builtin_amdgcn_s_setprio(1);
  acc0 = __builtin_amdgcn_mfma_f32_32x32x16_bf16(v0[0], pa0, acc0, 0, 0, 0);
  acc0 = __builtin_amdgcn_mfma_f32_32x32x16_bf16(v0[1], pa1, acc0, 0, 0, 0);
  acc1 = __builtin_amdgcn_mfma_f32_32x32x16_bf16(v1[0], pa0, acc1, 0, 0, 0);
  acc1 = __builtin_amdgcn_mfma_f32_32x32x16_bf16(v1[1], pa1, acc1, 0, 0, 0);
  __builtin_amdgcn_s_setprio(0);
}

DEVI void write_partial(float* M, int slot, const f32x16& a0, const f32x16& a1,
                        float m2, float l) {
#pragma unroll
  for (int r = 0; r < 16; ++r) { M[slot + r] = a0[r]; M[slot + 16 + r] = a1[r]; }
  M[slot + 32] = m2;
  M[slot + 33] = l;
}

DEVI void write_merged(unsigned short* __restrict__ Ob, const float* M, int slot,
                       const f32x16& acc0, const f32x16& acc1, float m2, float l_run,
                       int bh, int q0, int ln, int hi) {
  const float mp = M[slot + 32], lp = M[slot + 33];
  const float m = fmaxf(m2, mp);
  const float eo = exp2f(m2 - m), ep = exp2f(mp - m);
  const float il = 1.0f / (l_run * eo + lp * ep);
  const int b = bh >> 4, h = bh & 15;
  unsigned short* ob = Ob + ((size_t)(b * 2048 + q0 + ln)) * 1024 + h * 64;
#pragma unroll
  for (int g = 0; g < 4; ++g) {
    ushort4 o0, o1;
    o0.x = f2b((acc0[4 * g + 0] * eo + M[slot + 4 * g + 0] * ep) * il);
    o0.y = f2b((acc0[4 * g + 1] * eo + M[slot + 4 * g + 1] * ep) * il);
    o0.z = f2b((acc0[4 * g + 2] * eo + M[slot + 4 * g + 2] * ep) * il);
    o0.w = f2b((acc0[4 * g + 3] * eo + M[slot + 4 * g + 3] * ep) * il);
    o1.x = f2b((acc1[4 * g + 0] * eo + M[slot + 16 + 4 * g + 0] * ep) * il);
    o1.y = f2b((acc1[4 * g + 1] * eo + M[slot + 16 + 4 * g + 1] * ep) * il);
    o1.z = f2b((acc1[4 * g + 2] * eo + M[slot + 16 + 4 * g + 2] * ep) * il);
    o1.w = f2b((acc1[4 * g + 3] * eo + M[slot + 16 + 4 * g + 3] * ep) * il);
    *(ushort4*)&ob[8 * g + 4 * hi]      = o0;   // dt=0
    *(ushort4*)&ob[32 + 8 * g + 4 * hi] = o1;   // dt=1
  }
}

__global__ __launch_bounds__(512) void attn_kernel(
    const unsigned short* __restrict__ Qb, const unsigned short* __restrict__ Kb,
    const unsigned short* __restrict__ VTb, unsigned short* __restrict__ Ob) {
  __shared__ unsigned char smem[2][2][16384];   // [dbuf][half][K 8K | V 8K]
  const int tid = threadIdx.x;
  const int lane = tid & 63, wid = tid >> 6;
  const int ln = lane & 31, hi = lane >> 5;
  const int s = wid & 3, half = wid >> 2;
  const int bh = blockIdx.x;
  const int p = blockIdx.y;
  const int jA = 15 - p, jB = p;
  const unsigned short* Qh = Qb + (size_t)bh * 2048 * 64;
  const unsigned short* Kh = Kb + (size_t)bh * 2048 * 64;
  const unsigned short* Vh = VTb + (size_t)bh * 64 * 2048;

  f32x16 aA0 = {}, aA1 = {}, aB0 = {}, aB1 = {};
  float mA = -1e30f, lA = 0.f, mB = -1e30f, lB = 0.f;
  int it = 0;

  auto load_q = [&](int q0, bf16x8 qf[4]) {
    const unsigned short* pq = Qh + (size_t)(q0 + ln) * 64 + hi * 8;
#pragma unroll
    for (int t = 0; t < 4; ++t) qf[t] = *(const bf16x8*)(pq + t * 16);
  };
  auto run_phase = [&](int j, const bf16x8 qf[4], f32x16& acc0, f32x16& acc1,
                       float& m2, float& l_run, int q0, int nextFirst) {
    const int qg = q0 + ln;
    const int top = q0 >> 5;
    for (int kb = 0; kb <= j; ++kb, ++it) {
      const int nxt = (kb < j) ? (kb + 1) * 128 : nextFirst;
      if (nxt >= 0) stage128(Kh, Vh, nxt, &smem[(it + 1) & 1][0][0], tid);
      const unsigned char* bufK = &smem[it & 1][half][0];
      const unsigned char* bufV = bufK + 8192;
      const int t64 = 2 * kb + half;
#pragma unroll
      for (int s32 = 0; s32 < 2; ++s32) {
        const int g32 = 2 * t64 + s32;
        if (g32 <= top)
          attn_sub(bufK, bufV, qf, s32, g32 * 32, g32 == top, qg, ln, hi, m2, l_run, acc0, acc1);
      }
      __syncthreads();
    }
  };

  bf16x8 qfA[4];
  load_q(jA * 128 + s * 32, qfA);
  stage128(Kh, Vh, 0, &smem[0][0][0], tid);
  __syncthreads();
  run_phase(jA, qfA, aA0, aA1, mA, lA, jA * 128 + s * 32, /*nextFirst=*/0);
  bf16x8 qfB[4];
  load_q(jB * 128 + s * 32, qfB);
  run_phase(jB, qfB, aB0, aB1, mB, lB, jB * 128 + s * 32, /*nextFirst=*/-1);

  // ---- split-K merge between halves (flash combine), then final O writes ----
  float* M = (float*)&smem[0][0][0];          // 34 KB used of 64 KB
  const int slot = (s * 64 + lane) * 34;
  if (half == 1) write_partial(M, slot, aA0, aA1, mA, lA);
  __syncthreads();
  if (half == 0) write_merged(Ob, M, slot, aA0, aA1, mA, lA, bh, jA * 128 + s * 32, ln, hi);
  __syncthreads();
  if (half == 0) write_partial(M, slot, aB0, aB1, mB, lB);
  __syncthreads();
  if (half == 1) write_merged(Ob, M, slot, aB0, aB1, mB, lB, bh, jB * 128 + s * 32, ln, hi);
}

// ------------------------------------------------------------------
// GEMM2: out = Ob @ WoT^T, f32 epilogue. grid (8, 32)
// ------------------------------------------------------------------
__global__ __launch_bounds__(256) void gemm_out_kernel(
    const unsigned short* __restrict__ Ob, const unsigned short* __restrict__ WoT,
    float* __restrict__ out) {
  __shared__ unsigned short As[2][128 * 64];
  __shared__ unsigned short Bs[2][128 * 64];
  const int lane = threadIdx.x & 63, wid = threadIdx.x >> 6;
  const int m0 = blockIdx.y * 128, n0 = blockIdx.x * 128;
  const int wr = wid >> 1, wc = wid & 1;
  f32x4 acc[4][4] = {};
  gemm_mainloop(Ob, WoT, &As[0][0], &Bs[0][0], m0, n0, lane, wid, wr, wc, acc);
#pragma unroll
  for (int mi = 0; mi < 4; ++mi) {
    const int mrow = m0 + wr * 64 + mi * 16 + ((lane >> 4) << 2);
#pragma unroll
    for (int ni = 0; ni < 4; ++ni) {
      const int n = n0 + wc * 64 + ni * 16 + (lane & 15);
#pragma unroll
      for (int r = 0; r < 4; ++r)
        out[(size_t)(mrow + r) * 1024 + n] = acc[mi][ni][r];
    }
  }
}

// ------------------------------------------------------------------
extern "C" void kernel_launch(void* const* d_in, const int* in_sizes, int n_in,
                              void* d_out, int out_size, void* d_ws, size_t ws_size,
                              hipStream_t stream) {
  const float* x     = (const float*)d_in[0];
  const float* w_qkv = (const float*)d_in[1];
  const float* w_o   = (const float*)d_in[2];
  float* out = (float*)d_out;
  char* ws = (char*)d_ws;

  const size_t MB = 1 << 20;
  float* ct = (float*)(ws);                          // 256 KB
  float* st = (float*)(ws + (256 << 10));            // 256 KB
  unsigned short* Xb  = (unsigned short*)(ws + (512 << 10));            // 8 MB  (reused as Ob)
  unsigned short* WqT = (unsigned short*)(ws + (512 << 10) + 8  * MB);  // 6 MB
  unsigned short* WoT = (unsigned short*)(ws + (512 << 10) + 14 * MB);  // 2 MB
  unsigned short* Qb  = (unsigned short*)(ws + (512 << 10) + 16 * MB);  // 8 MB
  unsigned short* Kb  = (unsigned short*)(ws + (512 << 10) + 24 * MB);  // 8 MB
  unsigned short* VTb = (unsigned short*)(ws + (512 << 10) + 32 * MB);  // 8 MB
  unsigned short* Ob  = Xb;  // Xb dead after gemm1; total ws = 40.5 MB

  rope_table_kernel<<<dim3(256), dim3(256), 0, stream>>>(ct, st);
  cvt_x_kernel<<<dim3(4096), dim3(256), 0, stream>>>(x, Xb);
  transpose_kernel<<<dim3(96, 32), dim3(32, 8), 0, stream>>>(w_qkv, WqT, 1024, 3072);
  transpose_kernel<<<dim3(32, 32), dim3(32, 8), 0, stream>>>(w_o, WoT, 1024, 1024);
  gemm_qkv_kernel<<<dim3(12, 16), dim3(512), 0, stream>>>(Xb, WqT, ct, st, Qb, Kb, VTb);
  attn_kernel<<<dim3(32, 8), dim3(512), 0, stream>>>(Qb, Kb, VTb, Ob);
  gemm_out_kernel<<<dim3(8, 32), dim3(256), 0, stream>>>(Ob, WoT, out);
}